// Round 24
// baseline (2500.655 us; speedup 1.0000x reference)
//
#include <hip/hip_runtime.h>
#include <hip/hip_bf16.h>
#include <math.h>

#define NEG_SLOPE 0.2f
#define BM 64
#define BN 64
#define BK 16

typedef __hip_bfloat16 bf16;
typedef __attribute__((ext_vector_type(8))) short sh8;
typedef __attribute__((ext_vector_type(4))) float f32x4;

__device__ __forceinline__ float ldf(const float* p) { return *p; }
__device__ __forceinline__ float ldf(const bf16* p) { return __bfloat162float(*p); }
__device__ __forceinline__ void stf(float* p, float v) { *p = v; }
__device__ __forceinline__ void stf(bf16* p, float v) { *p = __float2bfloat16(v); }

// async global->LDS, 16B per lane; LDS dest is wave-linear (base + lane*16)
__device__ __forceinline__ void gload16(const void* g, void* l) {
  __builtin_amdgcn_global_load_lds(
      (__attribute__((address_space(1))) void*)(g),
      (__attribute__((address_space(3))) void*)(l), 16, 0, 0);
}

__device__ __forceinline__ float2 ld2f(const bf16* p) {
  unsigned int u = *(const unsigned int*)p;
  float2 r;
  r.x = __uint_as_float((u & 0xffffu) << 16);
  r.y = __uint_as_float(u & 0xffff0000u);
  return r;
}
__device__ __forceinline__ float2 ld2f(const float* p) { return *(const float2*)p; }
__device__ __forceinline__ void st2f(bf16* p, float a, float b) {
  bf16 t[2] = { __float2bfloat16(a), __float2bfloat16(b) };
  *(unsigned int*)p = *(unsigned int*)t;
}
__device__ __forceinline__ void st2f(float* p, float a, float b) {
  float2 v; v.x = a; v.y = b; *(float2*)p = v;
}

// 8 bf16 (uint4) -> 8 floats
__device__ __forceinline__ void unp8(uint4 u, float* o) {
  unsigned w0 = u.x, w1 = u.y, w2 = u.z, w3 = u.w;
  o[0] = __uint_as_float((w0 & 0xffffu) << 16); o[1] = __uint_as_float(w0 & 0xffff0000u);
  o[2] = __uint_as_float((w1 & 0xffffu) << 16); o[3] = __uint_as_float(w1 & 0xffff0000u);
  o[4] = __uint_as_float((w2 & 0xffffu) << 16); o[5] = __uint_as_float(w2 & 0xffff0000u);
  o[6] = __uint_as_float((w3 & 0xffffu) << 16); o[7] = __uint_as_float(w3 & 0xffff0000u);
}
__device__ __forceinline__ void st8(bf16* p, const float* v) {
  bf16 t[8];
#pragma unroll
  for (int j = 0; j < 8; ++j) t[j] = __float2bfloat16(v[j]);
  *(uint4*)p = *(uint4*)t;
}
__device__ __forceinline__ void st8(float* p, const float* v) {
  float4 a, b;
  a.x = v[0]; a.y = v[1]; a.z = v[2]; a.w = v[3];
  b.x = v[4]; b.y = v[5]; b.z = v[6]; b.w = v[7];
  *(float4*)p = a;
  *(float4*)(p + 4) = b;
}

__device__ __forceinline__ int eidx(const int* __restrict__ ei, int f64, long long j) {
  return f64 ? ei[2 * j] : ei[(size_t)j];
}

// ---------------- dtype detect + CSR build ----------------

__global__ void init_counts_kernel(int* counts, int* fill, int N, int* flag) {
  int i = blockIdx.x * blockDim.x + threadIdx.x;
  if (i < N) { counts[i] = 1; fill[i] = 0; }
  if (i == 0) *flag = 1;
}

__global__ void detect_kernel(const int* __restrict__ ei, int E, int* flag) {
  int i = blockIdx.x * blockDim.x + threadIdx.x;
  bool nz = (i < E) && (ei[2 * i + 1] != 0);
  if (__any(nz) && (threadIdx.x & 63) == 0) atomicAnd(flag, 0);
}

__global__ void count_kernel(const int* __restrict__ ei, int E,
                             const int* __restrict__ flag, int* __restrict__ counts) {
  int i = blockIdx.x * blockDim.x + threadIdx.x;
  if (i < E) {
    int d = eidx(ei, *flag, (long long)E + i);
    atomicAdd(&counts[d], 1);
  }
}

__global__ void scan_kernel(const int* __restrict__ counts, int* __restrict__ indptr, int N) {
  __shared__ int sums[256];
  __shared__ int offs[256];
  int t = threadIdx.x;
  int chunk = (N + 255) / 256;
  int lo = t * chunk;
  int hi = lo + chunk; if (hi > N) hi = N;
  int s = 0;
  for (int i = lo; i < hi; ++i) s += counts[i];
  sums[t] = s;
  __syncthreads();
  if (t == 0) {
    int acc = 0;
    for (int i = 0; i < 256; ++i) { offs[i] = acc; acc += sums[i]; }
    indptr[N] = acc;
  }
  __syncthreads();
  int acc = offs[t];
  for (int i = lo; i < hi; ++i) { indptr[i] = acc; acc += counts[i]; }
}

__global__ void fill_kernel(const int* __restrict__ ei, int E, int N,
                            const int* __restrict__ flag,
                            const int* __restrict__ indptr,
                            int* __restrict__ fill, int* __restrict__ csr_src,
                            int* __restrict__ csr_dst) {
  int i = blockIdx.x * blockDim.x + threadIdx.x;
  int total = E + N;
  if (i >= total) return;
  int s, d;
  if (i < E) { int f = *flag; s = eidx(ei, f, i); d = eidx(ei, f, (long long)E + i); }
  else       { s = i - E;  d = s; }
  int p = indptr[d] + atomicAdd(&fill[d], 1);
  csr_src[p] = s;
  csr_dst[p] = d;
}

__global__ void copy_kernel(const float* __restrict__ a, float* __restrict__ b, int n) {
  int i = blockIdx.x * blockDim.x + threadIdx.x;
  if (i < n) b[i] = a[i];
}

__global__ void f2b_kernel(const float* __restrict__ src, bf16* __restrict__ dst, int npair) {
  int i = blockIdx.x * blockDim.x + threadIdx.x;
  if (i >= npair) return;
  float2 v = *(const float2*)(src + 2 * i);
  st2f(dst + 2 * i, v.x, v.y);
}

// x [N,39] fp32 -> xb [N,64] bf16 zero-padded
__global__ void convert_pad_kernel(const float* __restrict__ x, bf16* __restrict__ xb, int N) {
  int i = blockIdx.x * blockDim.x + threadIdx.x;
  if (i >= N * 64) return;
  int n = i >> 6, c = i & 63;
  float v = (c < 39) ? x[(size_t)n * 39 + c] : 0.f;
  xb[i] = __float2bfloat16(v);
}

// transpose W [K,F] fp32 -> Wt [F,K] bf16
__global__ void transpose_w_kernel(const float* __restrict__ W, bf16* __restrict__ Wt,
                                   int K, int F) {
  int i = blockIdx.x * blockDim.x + threadIdx.x;
  if (i >= K * F) return;
  int f = i / K, k = i % K;
  Wt[i] = __float2bfloat16(W[(size_t)k * F + f]);
}

// transpose+pad: W [K,F] fp32 -> Wt [F,Kpad] bf16 (rows >= K are zero)
__global__ void transpose_w_pad_kernel(const float* __restrict__ W, bf16* __restrict__ Wt,
                                       int K, int Kpad, int F) {
  int i = blockIdx.x * blockDim.x + threadIdx.x;
  if (i >= F * Kpad) return;
  int f = i / Kpad, k = i % Kpad;
  float v = (k < K) ? W[(size_t)k * F + f] : 0.f;
  Wt[i] = __float2bfloat16(v);
}

// stacked K=128 table: WTs2 [1024][128] bf16; row f: k 0..38=Wl0[k][f], 64..102=Wr0[k-64][f]
__global__ void wstack2_kernel(const float* __restrict__ Wl0, const float* __restrict__ Wr0,
                               bf16* __restrict__ WTs2) {
  int i = blockIdx.x * blockDim.x + threadIdx.x;
  if (i >= 1024 * 128) return;
  int f = i >> 7, k = i & 127;
  float v = 0.f;
  if (k < 39) v = Wl0[(size_t)k * 1024 + f];
  else if (k >= 64 && k < 103) v = Wr0[(size_t)(k - 64) * 1024 + f];
  WTs2[i] = __float2bfloat16(v);
}

// ---------------- fused L1 edge score v5: 64 edges/wave, B prefetch pipeline ----------

__global__ __launch_bounds__(256)
void fused_score5_kernel(const bf16* __restrict__ xpad,
                         const bf16* __restrict__ WTs2,
                         const float* __restrict__ att,
                         const int* __restrict__ csr_src, const int* __restrict__ csr_dst,
                         float* __restrict__ ev, int Etot) {
  int tid = threadIdx.x;
  int lane = tid & 63;
  int wave = tid >> 6;
  int e0 = (blockIdx.x * 4 + wave) * 64;
  int rr = lane & 15;
  int kgo = (lane >> 4) * 8;
  sh8 af[4][4];
#pragma unroll
  for (int g = 0; g < 4; ++g) {
    int eg = e0 + g * 16 + rr;
    int s = (eg < Etot) ? csr_src[eg] : 0;
    int d = (eg < Etot) ? csr_dst[eg] : 0;
    af[g][0] = *(const sh8*)(xpad + (size_t)s * 64 + kgo);
    af[g][1] = *(const sh8*)(xpad + (size_t)s * 64 + 32 + kgo);
    af[g][2] = *(const sh8*)(xpad + (size_t)d * 64 + kgo);
    af[g][3] = *(const sh8*)(xpad + (size_t)d * 64 + 32 + kgo);
  }
  float el[4][4];
#pragma unroll
  for (int g = 0; g < 4; ++g)
#pragma unroll
    for (int j = 0; j < 4; ++j) el[g][j] = 0.f;

  // prologue: load cp=0 B-fragments + att
  const bf16* wrow0 = WTs2 + (size_t)rr * 128 + kgo;
  sh8 b0 = *(const sh8*)(wrow0);
  sh8 b1 = *(const sh8*)(wrow0 + 32);
  sh8 b2 = *(const sh8*)(wrow0 + 64);
  sh8 b3 = *(const sh8*)(wrow0 + 96);
  float a = att[rr];

  for (int cp = 0; cp < 64; ++cp) {
    // prefetch cp+1 (clamped; redundant last-iter load is harmless & cache-hot)
    int cpn = (cp < 63) ? cp + 1 : 63;
    int gcn = cpn * 16 + rr;
    const bf16* wrown = WTs2 + (size_t)gcn * 128 + kgo;
    sh8 nb0 = *(const sh8*)(wrown);
    sh8 nb1 = *(const sh8*)(wrown + 32);
    sh8 nb2 = *(const sh8*)(wrown + 64);
    sh8 nb3 = *(const sh8*)(wrown + 96);
    float na = att[gcn];

    f32x4 acc[4];
#pragma unroll
    for (int g = 0; g < 4; ++g) { acc[g][0] = 0.f; acc[g][1] = 0.f; acc[g][2] = 0.f; acc[g][3] = 0.f; }
#pragma unroll
    for (int g = 0; g < 4; ++g)
      acc[g] = __builtin_amdgcn_mfma_f32_16x16x32_bf16(af[g][0], b0, acc[g], 0, 0, 0);
#pragma unroll
    for (int g = 0; g < 4; ++g)
      acc[g] = __builtin_amdgcn_mfma_f32_16x16x32_bf16(af[g][1], b1, acc[g], 0, 0, 0);
#pragma unroll
    for (int g = 0; g < 4; ++g)
      acc[g] = __builtin_amdgcn_mfma_f32_16x16x32_bf16(af[g][2], b2, acc[g], 0, 0, 0);
#pragma unroll
    for (int g = 0; g < 4; ++g)
      acc[g] = __builtin_amdgcn_mfma_f32_16x16x32_bf16(af[g][3], b3, acc[g], 0, 0, 0);
#pragma unroll
    for (int g = 0; g < 4; ++g)
#pragma unroll
      for (int j = 0; j < 4; ++j) {
        float h = acc[g][j];
        h = fmaxf(h, NEG_SLOPE * h);   // leaky_relu (slope in (0,1))
        el[g][j] += a * h;
      }
    b0 = nb0; b1 = nb1; b2 = nb2; b3 = nb3; a = na;
  }
#pragma unroll
  for (int m = 1; m < 16; m <<= 1)
#pragma unroll
    for (int g = 0; g < 4; ++g)
#pragma unroll
      for (int j = 0; j < 4; ++j)
        el[g][j] += __shfl_xor(el[g][j], m);
  if ((lane & 15) == 0) {
    int rbase = (lane >> 4) * 4;
#pragma unroll
    for (int g = 0; g < 4; ++g)
#pragma unroll
      for (int j = 0; j < 4; ++j) {
        int e = e0 + g * 16 + rbase + j;
        if (e < Etot) ev[e] = el[g][j];
      }
  }
}

// x-space aggregation: 8 nodes/wave, 8-lane groups, uint4 loads
__global__ void agg64v_kernel(const bf16* __restrict__ xpad, const float* __restrict__ alpha,
                              const int* __restrict__ csr_src, const int* __restrict__ indptr,
                              bf16* __restrict__ xagg, int N) {
  int gid = blockIdx.x * blockDim.x + threadIdx.x;
  int lane = threadIdx.x & 63;
  int grp = lane >> 3, l8 = lane & 7;
  int node = (gid >> 6) * 8 + grp;
  if (node >= N) return;
  float acc[8] = {0.f, 0.f, 0.f, 0.f, 0.f, 0.f, 0.f, 0.f};
  int lo = indptr[node], hi = indptr[node + 1];
  for (int j = lo; j < hi; ++j) {
    float a = alpha[j];
    uint4 u = *(const uint4*)(xpad + (size_t)csr_src[j] * 64 + l8 * 8);
    float v[8]; unp8(u, v);
#pragma unroll
    for (int t = 0; t < 8; ++t) acc[t] += a * v[t];
  }
  st8(xagg + (size_t)node * 64 + l8 * 8, acc);
}

// edge score: 4 edges/wave, 16-lane groups, uint4 loads (bf16, Fc multiple of 128)
template <bool ACCUM>
__global__ void edge_vec4_kernel(const bf16* __restrict__ xl, int ldxl,
                                 const bf16* __restrict__ xr, int ldxr,
                                 const int* __restrict__ csr_src, const int* __restrict__ csr_dst,
                                 const float* __restrict__ att, float* __restrict__ ev,
                                 int Etot, int Fc) {
  int gid = blockIdx.x * blockDim.x + threadIdx.x;
  int lane = threadIdx.x & 63;
  int grp = lane >> 4, l16 = lane & 15;
  int edge = (gid >> 6) * 4 + grp;
  if (edge >= Etot) return;
  int s = csr_src[edge], d = csr_dst[edge];
  const bf16* pl = xl + (size_t)s * ldxl;
  const bf16* pr = xr + (size_t)d * ldxr;
  float acc = 0.f;
  for (int f0 = l16 * 8; f0 < Fc; f0 += 128) {
    uint4 ul = *(const uint4*)(pl + f0);
    uint4 ur = *(const uint4*)(pr + f0);
    float l[8], r[8];
    unp8(ul, l); unp8(ur, r);
    float4 a0 = *(const float4*)(att + f0);
    float4 a1 = *(const float4*)(att + f0 + 4);
    float at[8] = {a0.x, a0.y, a0.z, a0.w, a1.x, a1.y, a1.z, a1.w};
#pragma unroll
    for (int j = 0; j < 8; ++j) {
      float h = l[j] + r[j];
      h = fmaxf(h, NEG_SLOPE * h);
      acc += h * at[j];
    }
  }
#pragma unroll
  for (int m = 1; m < 16; m <<= 1) acc += __shfl_xor(acc, m);
  if (l16 == 0) {
    if (ACCUM) ev[edge] += acc;
    else ev[edge] = acc;
  }
}

template <bool ACCUM>
static void launch_edge4(const bf16* xl, int ldxl, const bf16* xr, int ldxr,
                         const int* cs, const int* cd, const float* att, float* ev,
                         int Etot, int Fc, hipStream_t st) {
  int blocks = (Etot + 15) / 16;
  edge_vec4_kernel<ACCUM><<<blocks, 256, 0, st>>>(xl, ldxl, xr, ldxr, cs, cd, att, ev, Etot, Fc);
}

// aggregation: 4 nodes/wave, 16-lane groups, uint4 loads (bf16 src; Fc = NC8*128)
template <int NC8, typename TD>
__global__ void agg4_kernel(const bf16* __restrict__ xl, int ldx,
                            const float* __restrict__ alpha,
                            const int* __restrict__ csr_src, const int* __restrict__ indptr,
                            const float* __restrict__ bias,
                            TD* __restrict__ out, int ldout, int N, int relu) {
  int gid = blockIdx.x * blockDim.x + threadIdx.x;
  int lane = threadIdx.x & 63;
  int grp = lane >> 4, l16 = lane & 15;
  int node = (gid >> 6) * 4 + grp;
  if (node >= N) return;
  float acc[NC8][8];
#pragma unroll
  for (int c = 0; c < NC8; ++c) {
    float4 b0 = *(const float4*)(bias + c * 128 + l16 * 8);
    float4 b1 = *(const float4*)(bias + c * 128 + l16 * 8 + 4);
    acc[c][0] = b0.x; acc[c][1] = b0.y; acc[c][2] = b0.z; acc[c][3] = b0.w;
    acc[c][4] = b1.x; acc[c][5] = b1.y; acc[c][6] = b1.z; acc[c][7] = b1.w;
  }
  int lo = indptr[node], hi = indptr[node + 1];
  for (int j = lo; j < hi; ++j) {
    float a = alpha[j];
    const bf16* row = xl + (size_t)csr_src[j] * ldx;
#pragma unroll
    for (int c = 0; c < NC8; ++c) {
      uint4 u = *(const uint4*)(row + c * 128 + l16 * 8);
      float v[8]; unp8(u, v);
#pragma unroll
      for (int t = 0; t < 8; ++t) acc[c][t] += a * v[t];
    }
  }
#pragma unroll
  for (int c = 0; c < NC8; ++c) {
    if (relu)
#pragma unroll
      for (int t = 0; t < 8; ++t) acc[c][t] = fmaxf(acc[c][t], 0.f);
    st8(&out[(size_t)node * ldout + c * 128 + l16 * 8], acc[c]);
  }
}

template <int NC8, typename TD>
static void launch_agg4(const bf16* xl, int ldx, const float* alpha, const int* cs,
                        const int* ip, const float* bias, TD* out, int ldout, int N, int relu,
                        hipStream_t st) {
  int blocks = (N + 15) / 16;
  agg4_kernel<NC8, TD><<<blocks, 256, 0, st>>>(xl, ldx, alpha, cs, ip, bias, out, ldout, N, relu);
}

// ---------------- MFMA GEMM (fp32 weights, scalar-staged; fallback only) ----------------

template <bool DUAL, bool ACCUM, typename TCL, typename TCR>
__global__ __launch_bounds__(256)
void mfma_gemm_kernel(const bf16* __restrict__ A, int lda, int M, int K, int Kw,
                      const float* __restrict__ Wl, const float* __restrict__ Wr,
                      int ldw,
                      TCL* __restrict__ Cl, int ldcl, TCR* __restrict__ Cr, int ldcr) {
  __shared__ short As[128 * 40];
  __shared__ short Bls[64 * 40];
  __shared__ short Brs[64 * 40];
  int tid = threadIdx.x;
  int lane = tid & 63;
  int wave = tid >> 6;
  int wm = wave >> 1, wn = wave & 1;
  int nwg = gridDim.x * gridDim.y;
  int orig = blockIdx.y * gridDim.x + blockIdx.x;
  int q = nwg >> 3, r = nwg & 7;
  int xcd = orig & 7;
  int base = (xcd < r) ? xcd * (q + 1) : r * (q + 1) + (xcd - r) * q;
  int wg = base + (orig >> 3);
  int bx = wg % gridDim.x;
  int by = wg / gridDim.x;
  int bm = by * 128, bn = bx * 64;
  f32x4 accl[4][2] = {};
  f32x4 accr[4][2] = {};
  int kg = lane >> 4;
  int rr = lane & 15;

  for (int k0 = 0; k0 < K; k0 += 32) {
#pragma unroll
    for (int i = 0; i < 2; ++i) {
      int c = tid + i * 256;
      int r2 = c >> 2, cg = c & 3;
      int gr = bm + r2;
      uint4 u = make_uint4(0u, 0u, 0u, 0u);
      if (gr < M) u = *(const uint4*)(A + (size_t)gr * lda + k0 + cg * 8);
      *(uint4*)(As + r2 * 40 + cg * 8) = u;
    }
    {
      int c = tid & 63, kb = tid >> 6;
      bf16 pl[8], pr[8];
#pragma unroll
      for (int j = 0; j < 8; ++j) {
        int kk = k0 + kb * 8 + j;
        float vl = 0.f, vr = 0.f;
        if (kk < Kw) {
          size_t w = (size_t)kk * ldw + bn + c;
          vl = Wl[w];
          if (DUAL) vr = Wr[w];
        }
        pl[j] = __float2bfloat16(vl);
        if (DUAL) pr[j] = __float2bfloat16(vr);
      }
      *(uint4*)(Bls + c * 40 + kb * 8) = *(uint4*)pl;
      if (DUAL) *(uint4*)(Brs + c * 40 + kb * 8) = *(uint4*)pr;
    }
    __syncthreads();
    sh8 af[4], blf[2], brf[2];
#pragma unroll
    for (int mi = 0; mi < 4; ++mi)
      af[mi] = *(const sh8*)(As + (wm * 64 + mi * 16 + rr) * 40 + kg * 8);
#pragma unroll
    for (int ni = 0; ni < 2; ++ni) {
      blf[ni] = *(const sh8*)(Bls + (wn * 32 + ni * 16 + rr) * 40 + kg * 8);
      if (DUAL) brf[ni] = *(const sh8*)(Brs + (wn * 32 + ni * 16 + rr) * 40 + kg * 8);
    }
#pragma unroll
    for (int mi = 0; mi < 4; ++mi)
#pragma unroll
      for (int ni = 0; ni < 2; ++ni) {
        accl[mi][ni] = __builtin_amdgcn_mfma_f32_16x16x32_bf16(af[mi], blf[ni], accl[mi][ni], 0, 0, 0);
        if (DUAL)
          accr[mi][ni] = __builtin_amdgcn_mfma_f32_16x16x32_bf16(af[mi], brf[ni], accr[mi][ni], 0, 0, 0);
      }
    __syncthreads();
  }
  int cr0 = (lane >> 4) * 4;
#pragma unroll
  for (int mi = 0; mi < 4; ++mi)
#pragma unroll
    for (int j = 0; j < 4; ++j) {
      int gr = bm + wm * 64 + mi * 16 + cr0 + j;
      if (gr >= M) continue;
#pragma unroll
      for (int ni = 0; ni < 2; ++ni) {
        int gc = bn + wn * 32 + ni * 16 + rr;
        float vl = accl[mi][ni][j];
        size_t ol = (size_t)gr * ldcl + gc;
        if (ACCUM) vl += ldf(&Cl[ol]);
        stf(&Cl[ol], vl);
        if (DUAL) {
          float vr = accr[mi][ni][j];
          size_t orr = (size_t)gr * ldcr + gc;
          if (ACCUM) vr += ldf(&Cr[orr]);
          stf(&Cr[orr], vr);
        }
      }
    }
}

template <bool DUAL, typename TCL, typename TCR>
static void launch_mfma(const bf16* A, int lda, int M, int K, int Kw,
                        const float* Wl, const float* Wr, int ldw, int Fc,
                        TCL* Cl, int ldcl, TCR* Cr, int ldcr, bool accum, hipStream_t st) {
  dim3 grid(Fc / 64, (M + 127) / 128);
  if (accum)
    mfma_gemm_kernel<DUAL, true, TCL, TCR><<<grid, 256, 0, st>>>(A, lda, M, K, Kw, Wl, Wr, ldw, Cl, ldcl, Cr, ldcr);
  else
    mfma_gemm_kernel<DUAL, false, TCL, TCR><<<grid, 256, 0, st>>>(A, lda, M, K, Kw, Wl, Wr, ldw, Cl, ldcl, Cr, ldcr);
}

// ---------------- MFMA GEMM (pre-transposed bf16 weights [F,K]) ----------------
// 128x128 tile (m97 geometry), global_load_lds staging, unpadded 32-short LDS rows.

template <bool DUAL, bool BIASRELU, typename TCL, typename TCR>
__global__ __launch_bounds__(256)
void mfma_wt_gemm_kernel(const bf16* __restrict__ A, int lda, int M, int K,
                         const bf16* __restrict__ WTl, const bf16* __restrict__ WTr,
                         const float* __restrict__ bias,
                         TCL* __restrict__ Cl, int ldcl, TCR* __restrict__ Cr, int ldcr) {
  __shared__ short As[128 * 32];
  __shared__ short Bls[128 * 32];
  __shared__ short Brs[128 * 32];
  int tid = threadIdx.x;
  int lane = tid & 63;
  int wave = tid >> 6;
  int wm = wave >> 1, wn = wave & 1;
  int nwg = gridDim.x * gridDim.y;
  int orig = blockIdx.y * gridDim.x + blockIdx.x;
  int q = nwg >> 3, r = nwg & 7;
  int xcd = orig & 7;
  int base = (xcd < r) ? xcd * (q + 1) : r * (q + 1) + (xcd - r) * q;
  int wg = base + (orig >> 3);
  int bx = wg % gridDim.x;
  int by = wg / gridDim.x;
  int bm = by * 128, bn = bx * 128;
  f32x4 accl[4][4] = {};
  f32x4 accr[4][4] = {};
  int kg = lane >> 4;
  int rr = lane & 15;

  // staging layout: LDS-linear chunk c (16B) = row-major (row = c>>2, cc = c&3)
  // A: 512 chunks (128 rows x 32 k) -> 2 issues/thread; B same.
  int c0 = wave * 64 + lane;        // 0..255
  int c1 = 256 + c0;                // 256..511
  int r0 = c0 >> 2, cc0 = c0 & 3;
  int r1 = c1 >> 2, cc1 = c1 & 3;
  int gra0 = bm + r0; if (gra0 >= M) gra0 = M - 1;   // clamp: garbage rows are discarded
  int gra1 = bm + r1; if (gra1 >= M) gra1 = M - 1;

  const bf16* pa0 = A + (size_t)gra0 * lda + cc0 * 8;
  const bf16* pa1 = A + (size_t)gra1 * lda + cc1 * 8;
  const bf16* pbl0 = WTl + (size_t)(bn + r0) * K + cc0 * 8;
  const bf16* pbl1 = WTl + (size_t)(bn + r1) * K + cc1 * 8;
  const bf16* pbr0 = WTr + (size_t)(bn + r0) * K + cc0 * 8;
  const bf16* pbr1 = WTr + (size_t)(bn + r1) * K + cc1 * 8;

  for (int k0 = 0; k0 < K; k0 += 32) {
    gload16(pa0 + k0, As + c0 * 8);
    gload16(pa1 + k0, As + c1 * 8);
    gload16(pbl0 + k0, Bls + c0 * 8);
    gload16(pbl1 + k0, Bls + c1 * 8);
    if (DUAL) {
      gload16(pbr0 + k0, Brs + c0 * 8);
      gload16(pbr1 + k0, Brs + c1 * 8);
    }
    __syncthreads();   // drains vmcnt(0) before barrier
    sh8 af[4], blf[4], brf[4];
#pragma unroll
    for (int mi = 0; mi < 4; ++mi)
      af[mi] = *(const sh8*)(As + (wm * 64 + mi * 16 + rr) * 32 + kg * 8);
#pragma unroll
    for (int ni = 0; ni < 4; ++ni) {
      blf[ni] = *(const sh8*)(Bls + (wn * 64 + ni * 16 + rr) * 32 + kg * 8);
      if (DUAL) brf[ni] = *(const sh8*)(Brs + (wn * 64 + ni * 16 + rr) * 32 + kg * 8);
    }
#pragma unroll
    for (int mi = 0; mi < 4; ++mi)
#pragma unroll
      for (int ni = 0; ni < 4; ++ni) {
        accl[mi][ni] = __builtin_amdgcn_mfma_f32_16x16x32_bf16(af[mi], blf[ni], accl[mi][ni], 0, 0, 0);
        if (DUAL)
          accr[mi][ni] = __builtin_amdgcn_mfma_f32_16x16x32_bf16(af[mi], brf[ni], accr[mi][ni], 0, 0, 0);
      }
    __syncthreads();
  }
  int cr0 = (lane >> 4) * 4;
#pragma unroll
  for (int mi = 0; mi < 4; ++mi)
#pragma unroll
    for (int j = 0; j < 4; ++j) {
      int gr = bm + wm * 64 + mi * 16 + cr0 + j;
      if (gr >= M) continue;
#pragma unroll
      for (int ni = 0; ni < 4; ++ni) {
        int gc = bn + wn * 64 + ni * 16 + rr;
        float vl = accl[mi][ni][j];
        if (BIASRELU) vl = fmaxf(vl + bias[gc], 0.f);
        stf(&Cl[(size_t)gr * ldcl + gc], vl);
        if (DUAL) stf(&Cr[(size_t)gr * ldcr + gc], accr[mi][ni][j]);
      }
    }
}

template <bool DUAL, bool BIASRELU, typename TCL, typename TCR>
static void launch_mfma_wt(const bf16* A, int lda, int M, int K,
                           const bf16* WTl, const bf16* WTr, const float* bias, int Fc,
                           TCL* Cl, int ldcl, TCR* Cr, int ldcr, hipStream_t st) {
  dim3 grid(Fc / 128, (M + 127) / 128);
  mfma_wt_gemm_kernel<DUAL, BIASRELU, TCL, TCR><<<grid, 256, 0, st>>>(A, lda, M, K, WTl, WTr,
                                                                      bias, Cl, ldcl, Cr, ldcr);
}

// ---------------- vector GEMM (fp32; slim L1 fallback + L5) ----------------

template <typename TA, typename TCL, typename TCR, bool DUAL, bool ACCUM>
__global__ __launch_bounds__(256)
void vgemm_kernel(const TA* __restrict__ A, int lda, int M, int K,
                  const float* __restrict__ Wl, const float* __restrict__ Wr,
                  int ldw, int Fc,
                  TCL* __restrict__ Cl, int ldcl, TCR* __restrict__ Cr, int ldcr) {
  __shared__ float As[BK][BM + 4];
  __shared__ float Bls[BK][BN];
  __shared__ float Brs[BK][BN];
  int tid = threadIdx.x;
  int tx = tid & 15, ty = tid >> 4;
  int bn = blockIdx.x * BN, bm = blockIdx.y * BM;
  float accl[4][4] = {};
  float accr[4][4] = {};
  for (int k0 = 0; k0 < K; k0 += BK) {
#pragma unroll
    for (int i = 0; i < 4; ++i) {
      int idx = tid + i * 256;
      int r = idx >> 4, c = idx & 15;
      int gr = bm + r, gc = k0 + c;
      As[c][r] = (gr < M && gc < K) ? ldf(&A[(size_t)gr * lda + gc]) : 0.f;
    }
#pragma unroll
    for (int i = 0; i < 4; ++i) {
      int idx = tid + i * 256;
      int c = idx >> 6, n = idx & 63;
      int gc = k0 + c, gn = bn + n;
      bool ok = (gc < K && gn < Fc);
      size_t w = (size_t)gc * ldw + gn;
      Bls[c][n] = ok ? Wl[w] : 0.f;
      if (DUAL) Brs[c][n] = ok ? Wr[w] : 0.f;
    }
    __syncthreads();
#pragma unroll
    for (int kk = 0; kk < BK; ++kk) {
      float4 a = *(const float4*)&As[kk][ty * 4];
      float4 bl = *(const float4*)&Bls[kk][tx * 4];
      float av[4] = {a.x, a.y, a.z, a.w};
      float blv[4] = {bl.x, bl.y, bl.z, bl.w};
      float brv[4] = {0.f, 0.f, 0.f, 0.f};
      if (DUAL) {
        float4 br = *(const float4*)&Brs[kk][tx * 4];
        brv[0] = br.x; brv[1] = br.y; brv[2] = br.z; brv[3] = br.w;
      }
#pragma unroll
      for (int i = 0; i < 4; ++i)
#pragma unroll
        for (int j = 0; j < 4; ++j) {
          accl[i][j] += av[i] * blv[j];
          if (DUAL) accr[i][j] += av[i] * brv[j];
        }
    }
    __syncthreads();
  }
#pragma unroll
  for (int i = 0; i < 4; ++i) {
    int gr = bm + ty * 4 + i;
    if (gr >= M) continue;
#pragma unroll
    for (int j = 0; j < 4; ++j) {
      int gn = bn + tx * 4 + j;
      if (gn >= Fc) continue;
      float vl = accl[i][j];
      size_t ol = (size_t)gr * ldcl + gn;
      if (ACCUM) vl += ldf(&Cl[ol]);
      stf(&Cl[ol], vl);
      if (DUAL) {
        float vr = accr[i][j];
        size_t orr = (size_t)gr * ldcr + gn;
        if (ACCUM) vr += ldf(&Cr[orr]);
        stf(&Cr[orr], vr);
      }
    }
  }
}

template <typename TA, typename TCL, typename TCR>
static void launch_vgemm(const TA* A, int lda, int M, int K,
                         const float* Wl, const float* Wr, int ldw, int Fc,
                         TCL* Cl, int ldcl, TCR* Cr, int ldcr, bool accum, hipStream_t st) {
  dim3 grid((Fc + BN - 1) / BN, (M + BM - 1) / BM);
  if (Wr) {
    if (accum) vgemm_kernel<TA, TCL, TCR, true, true><<<grid, 256, 0, st>>>(A, lda, M, K, Wl, Wr, ldw, Fc, Cl, ldcl, Cr, ldcr);
    else       vgemm_kernel<TA, TCL, TCR, true, false><<<grid, 256, 0, st>>>(A, lda, M, K, Wl, Wr, ldw, Fc, Cl, ldcl, Cr, ldcr);
  } else {
    if (accum) vgemm_kernel<TA, TCL, TCR, false, true><<<grid, 256, 0, st>>>(A, lda, M, K, Wl, Wl, ldw, Fc, Cl, ldcl, Cr, ldcr);
    else       vgemm_kernel<TA, TCL, TCR, false, false><<<grid, 256, 0, st>>>(A, lda, M, K, Wl, Wl, ldw, Fc, Cl, ldcl, Cr, ldcr);
  }
}

// ---------------- edge scores (scalar fallback variants) ----------------

template <typename TSL, typename TSR, bool ACCUM>
__global__ void edge_e_kernel(const TSL* __restrict__ xl, int ldxl,
                              const TSR* __restrict__ xr, int ldxr,
                              const int* __restrict__ csr_src, const int* __restrict__ csr_dst,
                              const float* __restrict__ att, float* __restrict__ ev,
                              int Etot, int Fc) {
  int gid = blockIdx.x * blockDim.x + threadIdx.x;
  int edge = gid >> 6;
  int lane = threadIdx.x & 63;
  if (edge >= Etot) return;
  int s = csr_src[edge], d = csr_dst[edge];
  const TSL* pl = xl + (size_t)s * ldxl;
  const TSR* pr = xr + (size_t)d * ldxr;
  float acc = 0.f;
  for (int f = lane; f < Fc; f += 64) {
    float h = ldf(&pl[f]) + ldf(&pr[f]);
    h = h > 0.f ? h : NEG_SLOPE * h;
    acc += h * att[f];
  }
#pragma unroll
  for (int off = 32; off > 0; off >>= 1) acc += __shfl_down(acc, off);
  if (lane == 0) {
    if (ACCUM) ev[edge] += acc;
    else ev[edge] = acc;
  }
}

template <typename TSL, typename TSR>
static void launch_edge(const TSL* xl, int ldxl, const TSR* xr, int ldxr,
                        const int* cs, const int* cd,
                        const float* att, float* ev, int Etot, int Fc, bool accum,
                        hipStream_t st) {
  int blocks = (int)(((long long)Etot * 64 + 255) / 256);
  if (accum) edge_e_kernel<TSL, TSR, true><<<blocks, 256, 0, st>>>(xl, ldxl, xr, ldxr, cs, cd, att, ev, Etot, Fc);
  else       edge_e_kernel<TSL, TSR, false><<<blocks, 256, 0, st>>>(xl, ldxl, xr, ldxr, cs, cd, att, ev, Etot, Fc);
}

template <typename TSL, typename TSR, bool ACCUM>
__global__ void edge_vec_kernel(const TSL* __restrict__ xl, int ldxl,
                                const TSR* __restrict__ xr, int ldxr,
                                const int* __restrict__ csr_src, const int* __restrict__ csr_dst,
                                const float* __restrict__ att, float* __restrict__ ev,
                                int Etot, int Fc) {
  int gid = blockIdx.x * blockDim.x + threadIdx.x;
  int edge = gid >> 6;
  int lane = threadIdx.x & 63;
  if (edge >= Etot) return;
  int s = csr_src[edge], d = csr_dst[edge];
  const TSL* pl = xl + (size_t)s * ldxl;
  const TSR* pr = xr + (size_t)d * ldxr;
  float acc = 0.f;
  for (int f = 2 * lane; f < Fc; f += 128) {
    float2 l = ld2f(pl + f);
    float2 r = ld2f(pr + f);
    float2 at = *(const float2*)(att + f);
    float h0 = l.x + r.x; h0 = h0 > 0.f ? h0 : NEG_SLOPE * h0;
    float h1 = l.y + r.y; h1 = h1 > 0.f ? h1 : NEG_SLOPE * h1;
    acc += h0 * at.x + h1 * at.y;
  }
#pragma unroll
  for (int off = 32; off > 0; off >>= 1) acc += __shfl_down(acc, off);
  if (lane == 0) {
    if (ACCUM) ev[edge] += acc;
    else ev[edge] = acc;
  }
}

template <typename TSL, typename TSR>
static void launch_edge_vec(const TSL* xl, int ldxl, const TSR* xr, int ldxr,
                            const int* cs, const int* cd,
                            const float* att, float* ev, int Etot, int Fc, bool accum,
                            hipStream_t st) {
  int blocks = (int)(((long long)Etot * 64 + 255) / 256);
  if (accum) edge_vec_kernel<TSL, TSR, true><<<blocks, 256, 0, st>>>(xl, ldxl, xr, ldxr, cs, cd, att, ev, Etot, Fc);
  else       edge_vec_kernel<TSL, TSR, false><<<blocks, 256, 0, st>>>(xl, ldxl, xr, ldxr, cs, cd, att, ev, Etot, Fc);
}

// ---------------- segment softmax ----------------

__global__ void softmax_kernel(float* __restrict__ ev, const int* __restrict__ indptr, int N) {
  int i = blockIdx.x * blockDim.x + threadIdx.x;
  if (i >= N) return;
  int lo = indptr[i], hi = indptr[i + 1];
  float m = -1e30f;
  for (int j = lo; j < hi; ++j) m = fmaxf(m, ev[j]);
  float s = 0.f;
  for (int j = lo; j < hi; ++j) { float x = expf(ev[j] - m); ev[j] = x; s += x; }
  float inv = 1.f / s;
  for (int j = lo; j < hi; ++j) ev[j] *= inv;
}

// ---------------- aggregation (scalar fallback; Fc = NP*128) ----------------

template <int NP, typename TS, typename TD>
__global__ void agg_vec_kernel(const TS* __restrict__ xl, int ldx,
                               const float* __restrict__ alpha,
                               const int* __restrict__ csr_src, const int* __restrict__ indptr,
                               const float* __restrict__ bias,
                               TD* __restrict__ out, int ldout, int N, int relu) {
  int gid = blockIdx.x * blockDim.x + threadIdx.x;
  int node = gid >> 6;
  int lane = threadIdx.x & 63;
  if (node >= N) return;
  float ax[NP], ay[NP];
#pragma unroll
  for (int p = 0; p < NP; ++p) {
    float2 b = *(const float2*)(bias + 2 * lane + p * 128);
    ax[p] = b.x; ay[p] = b.y;
  }
  int lo = indptr[node], hi = indptr[node + 1];
  for (int j = lo; j < hi; ++j) {
    float a = alpha[j];
    const TS* row = xl + (size_t)csr_src[j] * ldx;
#pragma unroll
    for (int p = 0; p < NP; ++p) {
      float2 v = ld2f(row + 2 * lane + p * 128);
      ax[p] += a * v.x;
      ay[p] += a * v.y;
    }
  }
#pragma unroll
  for (int p = 0; p < NP; ++p) {
    float vx = ax[p], vy = ay[p];
    if (relu) { vx = fmaxf(vx, 0.f); vy = fmaxf(vy, 0.f); }
    st2f(&out[(size_t)node * ldout + 2 * lane + p * 128], vx, vy);
  }
}

template <typename TS, typename TD>
static void launch_agg_vec(const TS* xl, int ldx, const float* alpha, const int* cs, const int* ip,
                           const float* bias, TD* out, int ldout, int N, int Fc, int relu,
                           hipStream_t st) {
  int blocks = (int)(((long long)N * 64 + 255) / 256);
  switch (Fc >> 7) {
    case 4: agg_vec_kernel<4, TS, TD><<<blocks, 256, 0, st>>>(xl, ldx, alpha, cs, ip, bias, out, ldout, N, relu); break;
    case 2: agg_vec_kernel<2, TS, TD><<<blocks, 256, 0, st>>>(xl, ldx, alpha, cs, ip, bias, out, ldout, N, relu); break;
    case 1: agg_vec_kernel<1, TS, TD><<<blocks, 256, 0, st>>>(xl, ldx, alpha, cs, ip, bias, out, ldout, N, relu); break;
  }
}

__global__ void aggregate3_kernel(const float* __restrict__ xl, const float* __restrict__ alpha,
                                  const int* __restrict__ csr_src, const int* __restrict__ indptr,
                                  const float* __restrict__ bias, float* __restrict__ out, int N) {
  int i = blockIdx.x * blockDim.x + threadIdx.x;
  if (i >= N) return;
  float a0 = bias[0], a1 = bias[1], a2 = bias[2];
  int lo = indptr[i], hi = indptr[i + 1];
  for (int j = lo; j < hi; ++j) {
    float a = alpha[j];
    const float* row = xl + (size_t)csr_src[j] * 3;
    a0 += a * row[0];
    a1 += a * row[1];
    a2 += a * row[2];
  }
  out[(size_t)i * 3 + 0] = a0;
  out[(size_t)i * 3 + 1] = a1;
  out[(size_t)i * 3 + 2] = a2;
}

// ---------------- launch ----------------

extern "C" void kernel_launch(void* const* d_in, const int* in_sizes, int n_in,
                              void* d_out, int out_size, void* d_ws, size_t ws_size,
                              hipStream_t stream) {
  const float* x = (const float*)d_in[0];
  const int* ei = (const int*)d_in[1];
  const int N = in_sizes[0] / 39;
  const int E = in_sizes[1] / 2;
  const int Etot = E + N;
  (void)n_in; (void)out_size;

  const float* Wl[5]; const float* Wr[5]; const float* att[5]; const float* bb[5];
  for (int l = 0; l < 5; ++l) {
    Wl[l]  = (const float*)d_in[2 + 4 * l];
    Wr[l]  = (const float*)d_in[3 + 4 * l];
    att[l] = (const float*)d_in[4 + 4 * l];
    bb[l]  = (const float*)d_in[5 + 4 * l];
  }

  char* ws = (char*)d_ws;
  size_t off = 0;
  auto alloc = [&](size_t b) -> char* {
    char* p = ws + off;
    off += (b + 255) & ~(size_t)255;
    return p;
  };
  int* counts  = (int*)alloc((size_t)N * 4);
  int* fillc   = (int*)alloc((size_t)N * 4);
  int* flag    = (int*)alloc(256);
  int* indptr  = (int*)alloc(((size_t)N + 1) * 4);
  int* csr_s   = (int*)alloc((size_t)Etot * 4);
  int* csr_d   = (int*)alloc((size_t)Etot * 4);
  float* ev    = (float*)alloc((size_t)Etot * 4);
  size_t small_end = off;

  const size_t fat4_need = small_end + (size_t)N * (2048 + 512) + 8192;
  const size_t slim_need = small_end + (size_t)Etot * 4 + (size_t)N * 2048 + 8192;
  if (ws_size < slim_need) return;

  const int tb = 256;
  init_counts_kernel<<<(N + tb - 1) / tb, tb, 0, stream>>>(counts, fillc, N, flag);
  detect_kernel<<<(E + tb - 1) / tb, tb, 0, stream>>>(ei, E, flag);
  count_kernel<<<(E + tb - 1) / tb, tb, 0, stream>>>(ei, E, flag, counts);
  scan_kernel<<<1, 256, 0, stream>>>(counts, indptr, N);
  fill_kernel<<<(Etot + tb - 1) / tb, tb, 0, stream>>>(ei, E, N, flag, indptr,
                                                       fillc, csr_s, csr_d);

  if (ws_size >= fat4_need) {
    // ======= FAT13: FAT12 + 128x128 mfma_wt =======
    char* OU = alloc((size_t)N * 2048);
    char* W1 = alloc((size_t)N * 512);
    bf16* out1 = (bf16*)OU;
    bf16* XLsc = (bf16*)OU;
    bf16* xpad = (bf16*)W1;
    bf16* xagg = (bf16*)(W1 + (size_t)N * 256);
    bf16* S0 = (bf16*)W1;
    bf16* S1 = (bf16*)(W1 + (size_t)N * 256);
    bf16* Dfull = (bf16*)d_out;
    bf16* D0 = (bf16*)d_out;
    bf16* D1 = (bf16*)d_out + (size_t)N * 128;

    const size_t wt_bytes = ((size_t)512 * 1024 + 256 * 512 + 128 * 256) * 2 * 2 + 2048;
    bool use_wt = (ws_size >= off + wt_bytes);
    bf16 *WT2l = nullptr, *WT2r = nullptr, *WT3l = nullptr, *WT3r = nullptr,
         *WT4l = nullptr, *WT4r = nullptr;
    if (use_wt) {
      WT2l = (bf16*)alloc((size_t)512 * 1024 * 2);
      WT2r = (bf16*)alloc((size_t)512 * 1024 * 2);
      WT3l = (bf16*)alloc((size_t)256 * 512 * 2);
      WT3r = (bf16*)alloc((size_t)256 * 512 * 2);
      WT4l = (bf16*)alloc((size_t)128 * 256 * 2);
      WT4r = (bf16*)alloc((size_t)128 * 256 * 2);
      transpose_w_kernel<<<(512 * 1024 + tb - 1) / tb, tb, 0, stream>>>(Wl[1], WT2l, 1024, 512);
      transpose_w_kernel<<<(512 * 1024 + tb - 1) / tb, tb, 0, stream>>>(Wr[1], WT2r, 1024, 512);
      transpose_w_kernel<<<(256 * 512 + tb - 1) / tb, tb, 0, stream>>>(Wl[2], WT3l, 512, 256);
      transpose_w_kernel<<<(256 * 512 + tb - 1) / tb, tb, 0, stream>>>(Wr[2], WT3r, 512, 256);
      transpose_w_kernel<<<(128 * 256 + tb - 1) / tb, tb, 0, stream>>>(Wl[3], WT4l, 256, 128);
      transpose_w_kernel<<<(128 * 256 + tb - 1) / tb, tb, 0, stream>>>(Wr[3], WT4r, 256, 128);
    }
    bool use_f1 = use_wt;
    bf16* WT0l = (bf16*)((char*)d_out + (size_t)N * 512);   // [1024][64]  (128 KB)
    bf16* WTs2 = WT0l + (size_t)1024 * 64;                  // [1024][128] (256 KB)
    if (use_f1) {
      transpose_w_pad_kernel<<<(1024 * 64 + tb - 1) / tb, tb, 0, stream>>>(Wl[0], WT0l, 39, 64, 1024);
      wstack2_kernel<<<(1024 * 128 + tb - 1) / tb, tb, 0, stream>>>(Wl[0], Wr[0], WTs2);
    }

    convert_pad_kernel<<<(N * 64 + tb - 1) / tb, tb, 0, stream>>>(x, xpad, N);

    if (use_f1) {
      fused_score5_kernel<<<(Etot + 255) / 256, 256, 0, stream>>>(xpad, WTs2, att[0],
                                                                  csr_s, csr_d, ev, Etot);
      softmax_kernel<<<(N + tb - 1) / tb, tb, 0, stream>>>(ev, indptr, N);
      agg64v_kernel<<<(N + 31) / 32, 256, 0, stream>>>(xpad, ev, csr_s, indptr, xagg, N);
      launch_mfma_wt<false, true, bf16, bf16>(xagg, 64, N, 64, WT0l, WT0l, bb[0], 1024,
                                              out1, 1024, out1, 1024, stream);
    } else {
      for (int kc = 0; kc < 4; ++kc) {
        launch_mfma<true, bf16, bf16>(xpad, 64, N, 64, 39, Wl[0] + kc * 256, Wr[0] + kc * 256,
                                      1024, 256, XLsc, 256, Dfull, 256, false, stream);
        launch_edge_vec<bf16, bf16>(XLsc, 256, Dfull, 256, csr_s, csr_d, att[0] + kc * 256,
                                    ev, Etot, 256, kc > 0, stream);
      }
      softmax_kernel<<<(N + tb - 1) / tb, tb, 0, stream>>>(ev, indptr, N);
      for (int kc = 0; kc < 4; ++kc) {
        launch_mfma<false, bf16, bf16>(xpad, 64, N, 64, 39, Wl[0] + kc * 256, Wl[0] + kc * 256,
                                       1024, 256, Dfull, 256, Dfull, 256, false, stream);
        launch_agg_vec<bf16, bf16>(Dfull, 256, ev, csr_s, indptr, bb[0] + kc * 256,
                                   out1 + kc * 256, 1024, N, 256, 1, stream);
      }
    }
    // xpad/xagg dead -> S0/S1 usable

    // L2 scores: XL fc0->S0 (evicted by fc3), fc1->S1, fc2->D0, fc3->S0; XR home D1
    bf16* xlslot[4] = { S0, S1, D0, S0 };
    for (int fc = 0; fc < 4; ++fc) {
      if (use_wt)
        launch_mfma_wt<true, false, bf16, bf16>(out1, 1024, N, 1024,
                                                WT2l + (size_t)fc * 128 * 1024,
                                                WT2r + (size_t)fc * 128 * 1024, nullptr, 128,
                                                xlslot[fc], 128, D1, 128, stream);
      else
        launch_mfma<true, bf16, bf16>(out1, 1024, N, 1024, 1024, Wl[1] + fc * 128, Wr[1] + fc * 128,
                                      512, 128, xlslot[fc], 128, D1, 128, false, stream);
      if (fc > 0)
        launch_edge4<true>(xlslot[fc], 128, D1, 128, csr_s, csr_d, att[1] + fc * 128, ev, Etot, 128, stream);
      else
        launch_edge4<false>(xlslot[fc], 128, D1, 128, csr_s, csr_d, att[1], ev, Etot, 128, stream);
    }
    softmax_kernel<<<(N + tb - 1) / tb, tb, 0, stream>>>(ev, indptr, N);
    if (use_wt)
      launch_mfma_wt<false, false, bf16, bf16>(out1, 1024, N, 1024, WT2l, WT2l, nullptr, 128,
                                               D1, 128, D1, 128, stream);
    else
      launch_mfma<false, bf16, bf16>(out1, 1024, N, 1024, 1024, Wl[1], Wl[1],
                                     512, 128, D1, 128, D1, 128, false, stream);
    bf16* out2 = (bf16*)OU;
    launch_agg4<1, bf16>(D1, 128, ev, csr_s, indptr, bb[1] + 0 * 128, out2 + 0 * 128, 512, N, 1, stream);
    launch_agg4<1, bf16>(S1, 128, ev, csr_s, indptr, bb[1] + 1 * 128, out2 + 1 * 128, 512, N, 1, stream);
    launch_agg4<1, bf16>(D0, 128, ev, csr_s, indptr, bb[1] + 2 * 128, out2 + 2 * 128, 512, N, 1, stream);
    launch_agg4<1, bf16>(S0, 128, ev, csr_s, indptr, bb[1] + 3 * 128, out2 + 3 * 128, 512, N, 1, stream);

    // L3
    bf16* XL3 = (bf16*)(OU + (size_t)N * 1024);
    bf16* XR3 = (bf16*)(OU + (size_t)N * 1536);
    if (use_wt)
      launch_mfma_wt<true, false, bf16, bf16>(out2, 512, N, 512, WT3l, WT3r, nullptr, 256,
                                              XL3, 256, XR3, 256, stream);
    else
      launch_mfma<true, bf16, bf16>(out2, 512, N, 512, 512, Wl[2], Wr[2], 256, 256,
                                    XL3, 256, XR3, 256, false, stream);
    launch_edge4<false>(XL3, 256, XR3, 256, csr_s, csr_d, att[2], ev, Etot, 256, stream);
    softmax_kernel<<<(N + tb - 1) / tb, tb, 0, stream>>>(ev, indptr, N);
    bf16* out3 = XR3;
    launch_agg4<2, bf16>(XL3, 256, ev, csr_s, indptr, bb[2], out3, 256, N, 1, stream);

    // L4 -> d_out fp32
    bf16* XL4 = (bf16*)OU;
    bf16* XR4 = (bf16*)(OU + (size_t)N * 256);
    if (use_wt)
      launch_mfma_wt<true, false, bf16, bf16>(out3, 256, N, 256, WT4l, WT4r, nullptr, 128,
                                              XL4, 128, XR4, 128, stream);
    else
      launch_mfma<true, bf16, bf16>(out3, 256, N, 256, 256, Wl[3], Wr[3], 128, 128,
                                    XL4, 128, XR4, 128, false, stream);
    launch_edge4<false>(XL4, 128, XR4, 128, csr_s, csr_d, att[3], ev, Etot, 128, stream);
    softmax_kernel<<<(N + tb - 1) / tb, tb, 0, stream>>>(ev, indptr, N);
    launch_agg4<1, float>(XL4, 128, ev, csr_s, indptr, bb[3], (float*)d_out, 128, N, 1, stream);

    // L5
    float* XL5 = (float*)W1;
    float* XR5 = (float*)(W1 + (((size_t)N * 12 + 255) & ~(size_t)255));
    launch_vgemm<float, float, float>((const float*)d_out, 128, N, 128, Wl[4], Wr[4], 3, 3,
                                      XL5, 3, XR5, 3, false, stream);
    launch_edge<float, float>(XL5, 3, XR5, 3, csr_s, csr_d, att[4], ev, Etot, 3, false, stream);
    softmax_kernel<<<(N + tb - 1) / tb, tb, 0, stream>>>(ev, indptr, N);
    aggregate3_kernel<<<(N + tb - 1) / tb, tb, 0, stream>>>(XL5, ev, csr_s, indptr, bb[4],
                                                            (float*)d_out + (size_t)N * 128, N);
    return;
  }

  // ============ SLIM-5 (verified fallback) ============
  float* alpha1 = (float*)alloc((size_t)Etot * 4);
  char* R0 = alloc((size_t)N * 256);
  char* R1 = alloc((size_t)N * 256);
  char* R2 = alloc((size_t)N * 512);
  char* R3 = alloc((size_t)N * 512);
  char* R4 = alloc((size_t)N * 512);
  (void)R4;
  size_t base_need = off + 4096;
  bool use_xpad = (ws_size >= base_need + (size_t)N * 128 + 256);
  bf16* xpad = use_xpad ? (bf16*)alloc((size_t)N * 128) : nullptr;

  bf16* xl1c = (bf16*)R0;
  bf16* t1   = (bf16*)R1;
  float* waccL = (float*)R2;
  float* waccR = (float*)R3;
  bf16* out2 = (bf16*)R3;
  bf16* dXL1 = (bf16*)d_out;
  bf16* dXL2 = (bf16*)d_out + (size_t)N * 128;

  if (use_xpad)
    convert_pad_kernel<<<(N * 64 + tb - 1) / tb, tb, 0, stream>>>(x, xpad, N);

  for (int kc = 0; kc < 8; ++kc) {
    if (use_xpad)
      launch_mfma<true, bf16, bf16>(xpad, 64, N, 64, 39, Wl[0] + kc * 128, Wr[0] + kc * 128,
                                    1024, 128, xl1c, 128, t1, 128, false, stream);
    else
      launch_vgemm<float, bf16, bf16>(x, 39, N, 39, Wl[0] + kc * 128, Wr[0] + kc * 128, 1024, 128,
                                      xl1c, 128, t1, 128, false, stream);
    launch_edge_vec<bf16, bf16>(xl1c, 128, t1, 128, csr_s, csr_d, att[0] + kc * 128,
                                ev, Etot, 128, kc > 0, stream);
  }
  softmax_kernel<<<(N + tb - 1) / tb, tb, 0, stream>>>(ev, indptr, N);
  copy_kernel<<<(Etot + tb - 1) / tb, tb, 0, stream>>>(ev, alpha1, Etot);

  auto mat_out1 = [&](int kc) {
    if (use_xpad)
      launch_mfma<false, bf16, bf16>(xpad, 64, N, 64, 39, Wl[0] + kc * 128, Wl[0] + kc * 128,
                                     1024, 128, xl1c, 128, xl1c, 128, false, stream);
    else
      launch_vgemm<float, bf16, bf16>(x, 39, N, 39, Wl[0] + kc * 128, nullptr, 1024, 128,
                                      xl1c, 128, xl1c, 128, false, stream);
    launch_agg_vec<bf16, bf16>(xl1c, 128, alpha1, csr_s, indptr, bb[0] + kc * 128,
                               t1, 128, N, 128, 1, stream);
  };

  for (int fc = 0; fc < 4; ++fc) {
    for (int kc = 0; kc < 8; ++kc) {
      mat_out1(kc);
      const float* wl = Wl[1] + (size_t)kc * 128 * 512 + fc * 128;
      const float* wr = Wr[1] + (size_t)kc * 128 * 512 + fc * 128;
      launch_mfma<true, float, float>(t1, 128, N, 128, 128, wl, wr, 512, 128,
                                      waccL, 128, waccR, 128, kc > 0, stream);
    }
    launch_edge_vec<float, float>(waccL, 128, waccR, 128, csr_s, csr_d,
                                  att[1] + fc * 128, ev, Etot, 128, fc > 0, stream);
    if (fc == 1)
      f2b_kernel<<<(N * 64 + tb - 1) / tb, tb, 0, stream>>>(waccL, dXL1, N * 64);
    if (fc == 2)
      f2b_kernel<<<(N * 64 + tb - 1) / tb, tb, 0, stream>>>(waccL, dXL2, N * 64);
  }
  softmax_kernel<<<(N + tb - 1) / tb, tb, 0, stream>>>(ev, indptr, N);

  launch_agg_vec<float, bf16>(waccL, 128, ev, csr_s, indptr, bb[1] + 3 * 128,
                              out2 + 3 * 128, 512, N, 128, 1, stream);
  launch_agg_vec<bf16, bf16>(dXL1, 128, ev, csr_s, indptr, bb[1] + 1 * 128,
                             out2 + 1 * 128, 512, N, 128, 1, stream);
  launch_agg_vec<bf16, bf16>(dXL2, 128, ev, csr_s, indptr, bb[1] + 2 * 128,
                             out2 + 2 * 128, 512, N, 128, 1, stream);
  for (int kc = 0; kc < 8; ++kc) {
    mat_out1(kc);
    const float* wl = Wl[1] + (size_t)kc * 128 * 512;
    launch_mfma<false, float, float>(t1, 128, N, 128, 128, wl, wl, 512, 128,
                                     waccL, 128, waccL, 128, kc > 0, stream);
  }
  launch_agg_vec<float, bf16>(waccL, 128, ev, csr_s, indptr, bb[1],
                              out2, 512, N, 128, 1, stream);

  bf16* XL3 = (bf16*)R2;
  bf16* XR3 = (bf16*)R0;
  launch_mfma<true, bf16, bf16>(out2, 512, N, 512, 512, Wl[2], Wr[2], 256, 256,
                                XL3, 256, XR3, 256, false, stream);
  launch_edge_vec<bf16, bf16>(XL3, 256, XR3, 256, csr_s, csr_d, att[2], ev, Etot, 256, false, stream);
  softmax_kernel<<<(N + tb - 1) / tb, tb, 0, stream>>>(ev, indptr, N);
  bf16* out3 = XR3;
  launch_agg_vec<bf16, bf16>(XL3, 256, ev, csr_s, indptr, bb[2], out3, 256, N, 256, 1, stream);

  bf16* XL4 = (bf16*)R2;
  bf16* XR4 = (bf16*)(R2 + (size_t)N * 256);
  launch_mfma<true, bf16, bf16>(out3, 256, N, 256, 256, Wl[3], Wr[3], 128, 128,
                                XL4, 128, XR4, 128, false, stream);
  launch_edge_vec<bf16, bf16>(XL4, 128, XR4, 128, csr_s, csr_d, att[3], ev, Etot, 128, false, stream);
  softmax_kernel<<<(N + tb - 1) / tb, tb, 0, stream>>>(ev, indptr, N);
  launch_agg_vec<bf16, float>(XL4, 128, ev, csr_s, indptr, bb[3], (float*)d_out, 128, N, 128, 1, stream);

  float* XL5 = (float*)R3;
  float* XR5 = (float*)(R3 + (((size_t)N * 12 + 255) & ~(size_t)255));
  launch_vgemm<float, float, float>((const float*)d_out, 128, N, 128, Wl[4], Wr[4], 3, 3,
                                    XL5, 3, XR5, 3, false, stream);
  launch_edge<float, float>(XL5, 3, XR5, 3, csr_s, csr_d, att[4], ev, Etot, 3, false, stream);
  softmax_kernel<<<(N + tb - 1) / tb, tb, 0, stream>>>(ev, indptr, N);
  aggregate3_kernel<<<(N + tb - 1) / tb, tb, 0, stream>>>(XL5, ev, csr_s, indptr, bb[4],
                                                          (float*)d_out + (size_t)N * 128, N);
}

// Round 25
// 2131.574 us; speedup vs baseline: 1.1731x; 1.1731x over previous
//
#include <hip/hip_runtime.h>
#include <hip/hip_bf16.h>
#include <math.h>

#define NEG_SLOPE 0.2f
#define BM 64
#define BN 64
#define BK 16

typedef __hip_bfloat16 bf16;
typedef __attribute__((ext_vector_type(8))) short sh8;
typedef __attribute__((ext_vector_type(4))) float f32x4;

__device__ __forceinline__ float ldf(const float* p) { return *p; }
__device__ __forceinline__ float ldf(const bf16* p) { return __bfloat162float(*p); }
__device__ __forceinline__ void stf(float* p, float v) { *p = v; }
__device__ __forceinline__ void stf(bf16* p, float v) { *p = __float2bfloat16(v); }

// async global->LDS, 16B per lane; LDS dest is wave-linear (base + lane*16)
__device__ __forceinline__ void gload16(const void* g, void* l) {
  __builtin_amdgcn_global_load_lds(
      (__attribute__((address_space(1))) void*)(g),
      (__attribute__((address_space(3))) void*)(l), 16, 0, 0);
}

__device__ __forceinline__ float2 ld2f(const bf16* p) {
  unsigned int u = *(const unsigned int*)p;
  float2 r;
  r.x = __uint_as_float((u & 0xffffu) << 16);
  r.y = __uint_as_float(u & 0xffff0000u);
  return r;
}
__device__ __forceinline__ float2 ld2f(const float* p) { return *(const float2*)p; }
__device__ __forceinline__ void st2f(bf16* p, float a, float b) {
  bf16 t[2] = { __float2bfloat16(a), __float2bfloat16(b) };
  *(unsigned int*)p = *(unsigned int*)t;
}
__device__ __forceinline__ void st2f(float* p, float a, float b) {
  float2 v; v.x = a; v.y = b; *(float2*)p = v;
}

// 8 bf16 (uint4) -> 8 floats
__device__ __forceinline__ void unp8(uint4 u, float* o) {
  unsigned w0 = u.x, w1 = u.y, w2 = u.z, w3 = u.w;
  o[0] = __uint_as_float((w0 & 0xffffu) << 16); o[1] = __uint_as_float(w0 & 0xffff0000u);
  o[2] = __uint_as_float((w1 & 0xffffu) << 16); o[3] = __uint_as_float(w1 & 0xffff0000u);
  o[4] = __uint_as_float((w2 & 0xffffu) << 16); o[5] = __uint_as_float(w2 & 0xffff0000u);
  o[6] = __uint_as_float((w3 & 0xffffu) << 16); o[7] = __uint_as_float(w3 & 0xffff0000u);
}
__device__ __forceinline__ void st8(bf16* p, const float* v) {
  bf16 t[8];
#pragma unroll
  for (int j = 0; j < 8; ++j) t[j] = __float2bfloat16(v[j]);
  *(uint4*)p = *(uint4*)t;
}
__device__ __forceinline__ void st8(float* p, const float* v) {
  float4 a, b;
  a.x = v[0]; a.y = v[1]; a.z = v[2]; a.w = v[3];
  b.x = v[4]; b.y = v[5]; b.z = v[6]; b.w = v[7];
  *(float4*)p = a;
  *(float4*)(p + 4) = b;
}

__device__ __forceinline__ int eidx(const int* __restrict__ ei, int f64, long long j) {
  return f64 ? ei[2 * j] : ei[(size_t)j];
}

// ---------------- dtype detect + CSR build ----------------

__global__ void init_counts_kernel(int* counts, int* fill, int N, int* flag) {
  int i = blockIdx.x * blockDim.x + threadIdx.x;
  if (i < N) { counts[i] = 1; fill[i] = 0; }
  if (i == 0) *flag = 1;
}

__global__ void detect_kernel(const int* __restrict__ ei, int E, int* flag) {
  int i = blockIdx.x * blockDim.x + threadIdx.x;
  bool nz = (i < E) && (ei[2 * i + 1] != 0);
  if (__any(nz) && (threadIdx.x & 63) == 0) atomicAnd(flag, 0);
}

__global__ void count_kernel(const int* __restrict__ ei, int E,
                             const int* __restrict__ flag, int* __restrict__ counts) {
  int i = blockIdx.x * blockDim.x + threadIdx.x;
  if (i < E) {
    int d = eidx(ei, *flag, (long long)E + i);
    atomicAdd(&counts[d], 1);
  }
}

__global__ void scan_kernel(const int* __restrict__ counts, int* __restrict__ indptr, int N) {
  __shared__ int sums[256];
  __shared__ int offs[256];
  int t = threadIdx.x;
  int chunk = (N + 255) / 256;
  int lo = t * chunk;
  int hi = lo + chunk; if (hi > N) hi = N;
  int s = 0;
  for (int i = lo; i < hi; ++i) s += counts[i];
  sums[t] = s;
  __syncthreads();
  if (t == 0) {
    int acc = 0;
    for (int i = 0; i < 256; ++i) { offs[i] = acc; acc += sums[i]; }
    indptr[N] = acc;
  }
  __syncthreads();
  int acc = offs[t];
  for (int i = lo; i < hi; ++i) { indptr[i] = acc; acc += counts[i]; }
}

__global__ void fill_kernel(const int* __restrict__ ei, int E, int N,
                            const int* __restrict__ flag,
                            const int* __restrict__ indptr,
                            int* __restrict__ fill, int* __restrict__ csr_src,
                            int* __restrict__ csr_dst) {
  int i = blockIdx.x * blockDim.x + threadIdx.x;
  int total = E + N;
  if (i >= total) return;
  int s, d;
  if (i < E) { int f = *flag; s = eidx(ei, f, i); d = eidx(ei, f, (long long)E + i); }
  else       { s = i - E;  d = s; }
  int p = indptr[d] + atomicAdd(&fill[d], 1);
  csr_src[p] = s;
  csr_dst[p] = d;
}

__global__ void copy_kernel(const float* __restrict__ a, float* __restrict__ b, int n) {
  int i = blockIdx.x * blockDim.x + threadIdx.x;
  if (i < n) b[i] = a[i];
}

__global__ void f2b_kernel(const float* __restrict__ src, bf16* __restrict__ dst, int npair) {
  int i = blockIdx.x * blockDim.x + threadIdx.x;
  if (i >= npair) return;
  float2 v = *(const float2*)(src + 2 * i);
  st2f(dst + 2 * i, v.x, v.y);
}

// x [N,39] fp32 -> xb [N,64] bf16 zero-padded
__global__ void convert_pad_kernel(const float* __restrict__ x, bf16* __restrict__ xb, int N) {
  int i = blockIdx.x * blockDim.x + threadIdx.x;
  if (i >= N * 64) return;
  int n = i >> 6, c = i & 63;
  float v = (c < 39) ? x[(size_t)n * 39 + c] : 0.f;
  xb[i] = __float2bfloat16(v);
}

// transpose W [K,F] fp32 -> Wt [F,K] bf16
__global__ void transpose_w_kernel(const float* __restrict__ W, bf16* __restrict__ Wt,
                                   int K, int F) {
  int i = blockIdx.x * blockDim.x + threadIdx.x;
  if (i >= K * F) return;
  int f = i / K, k = i % K;
  Wt[i] = __float2bfloat16(W[(size_t)k * F + f]);
}

// transpose+pad: W [K,F] fp32 -> Wt [F,Kpad] bf16 (rows >= K are zero)
__global__ void transpose_w_pad_kernel(const float* __restrict__ W, bf16* __restrict__ Wt,
                                       int K, int Kpad, int F) {
  int i = blockIdx.x * blockDim.x + threadIdx.x;
  if (i >= F * Kpad) return;
  int f = i / Kpad, k = i % Kpad;
  float v = (k < K) ? W[(size_t)k * F + f] : 0.f;
  Wt[i] = __float2bfloat16(v);
}

// stacked K=128 table: WTs2 [1024][128] bf16; row f: k 0..38=Wl0[k][f], 64..102=Wr0[k-64][f]
__global__ void wstack2_kernel(const float* __restrict__ Wl0, const float* __restrict__ Wr0,
                               bf16* __restrict__ WTs2) {
  int i = blockIdx.x * blockDim.x + threadIdx.x;
  if (i >= 1024 * 128) return;
  int f = i >> 7, k = i & 127;
  float v = 0.f;
  if (k < 39) v = Wl0[(size_t)k * 1024 + f];
  else if (k >= 64 && k < 103) v = Wr0[(size_t)(k - 64) * 1024 + f];
  WTs2[i] = __float2bfloat16(v);
}

// ---------------- fused L1 edge score v5: 64 edges/wave, B prefetch pipeline ----------

__global__ __launch_bounds__(256)
void fused_score5_kernel(const bf16* __restrict__ xpad,
                         const bf16* __restrict__ WTs2,
                         const float* __restrict__ att,
                         const int* __restrict__ csr_src, const int* __restrict__ csr_dst,
                         float* __restrict__ ev, int Etot) {
  int tid = threadIdx.x;
  int lane = tid & 63;
  int wave = tid >> 6;
  int e0 = (blockIdx.x * 4 + wave) * 64;
  int rr = lane & 15;
  int kgo = (lane >> 4) * 8;
  sh8 af[4][4];
#pragma unroll
  for (int g = 0; g < 4; ++g) {
    int eg = e0 + g * 16 + rr;
    int s = (eg < Etot) ? csr_src[eg] : 0;
    int d = (eg < Etot) ? csr_dst[eg] : 0;
    af[g][0] = *(const sh8*)(xpad + (size_t)s * 64 + kgo);
    af[g][1] = *(const sh8*)(xpad + (size_t)s * 64 + 32 + kgo);
    af[g][2] = *(const sh8*)(xpad + (size_t)d * 64 + kgo);
    af[g][3] = *(const sh8*)(xpad + (size_t)d * 64 + 32 + kgo);
  }
  float el[4][4];
#pragma unroll
  for (int g = 0; g < 4; ++g)
#pragma unroll
    for (int j = 0; j < 4; ++j) el[g][j] = 0.f;

  // prologue: load cp=0 B-fragments + att
  const bf16* wrow0 = WTs2 + (size_t)rr * 128 + kgo;
  sh8 b0 = *(const sh8*)(wrow0);
  sh8 b1 = *(const sh8*)(wrow0 + 32);
  sh8 b2 = *(const sh8*)(wrow0 + 64);
  sh8 b3 = *(const sh8*)(wrow0 + 96);
  float a = att[rr];

  for (int cp = 0; cp < 64; ++cp) {
    // prefetch cp+1 (clamped; redundant last-iter load is harmless & cache-hot)
    int cpn = (cp < 63) ? cp + 1 : 63;
    int gcn = cpn * 16 + rr;
    const bf16* wrown = WTs2 + (size_t)gcn * 128 + kgo;
    sh8 nb0 = *(const sh8*)(wrown);
    sh8 nb1 = *(const sh8*)(wrown + 32);
    sh8 nb2 = *(const sh8*)(wrown + 64);
    sh8 nb3 = *(const sh8*)(wrown + 96);
    float na = att[gcn];

    f32x4 acc[4];
#pragma unroll
    for (int g = 0; g < 4; ++g) { acc[g][0] = 0.f; acc[g][1] = 0.f; acc[g][2] = 0.f; acc[g][3] = 0.f; }
#pragma unroll
    for (int g = 0; g < 4; ++g)
      acc[g] = __builtin_amdgcn_mfma_f32_16x16x32_bf16(af[g][0], b0, acc[g], 0, 0, 0);
#pragma unroll
    for (int g = 0; g < 4; ++g)
      acc[g] = __builtin_amdgcn_mfma_f32_16x16x32_bf16(af[g][1], b1, acc[g], 0, 0, 0);
#pragma unroll
    for (int g = 0; g < 4; ++g)
      acc[g] = __builtin_amdgcn_mfma_f32_16x16x32_bf16(af[g][2], b2, acc[g], 0, 0, 0);
#pragma unroll
    for (int g = 0; g < 4; ++g)
      acc[g] = __builtin_amdgcn_mfma_f32_16x16x32_bf16(af[g][3], b3, acc[g], 0, 0, 0);
#pragma unroll
    for (int g = 0; g < 4; ++g)
#pragma unroll
      for (int j = 0; j < 4; ++j) {
        float h = acc[g][j];
        h = fmaxf(h, NEG_SLOPE * h);   // leaky_relu (slope in (0,1))
        el[g][j] += a * h;
      }
    b0 = nb0; b1 = nb1; b2 = nb2; b3 = nb3; a = na;
  }
#pragma unroll
  for (int m = 1; m < 16; m <<= 1)
#pragma unroll
    for (int g = 0; g < 4; ++g)
#pragma unroll
      for (int j = 0; j < 4; ++j)
        el[g][j] += __shfl_xor(el[g][j], m);
  if ((lane & 15) == 0) {
    int rbase = (lane >> 4) * 4;
#pragma unroll
    for (int g = 0; g < 4; ++g)
#pragma unroll
      for (int j = 0; j < 4; ++j) {
        int e = e0 + g * 16 + rbase + j;
        if (e < Etot) ev[e] = el[g][j];
      }
  }
}

// x-space aggregation: 8 nodes/wave, 8-lane groups, uint4 loads
__global__ void agg64v_kernel(const bf16* __restrict__ xpad, const float* __restrict__ alpha,
                              const int* __restrict__ csr_src, const int* __restrict__ indptr,
                              bf16* __restrict__ xagg, int N) {
  int gid = blockIdx.x * blockDim.x + threadIdx.x;
  int lane = threadIdx.x & 63;
  int grp = lane >> 3, l8 = lane & 7;
  int node = (gid >> 6) * 8 + grp;
  if (node >= N) return;
  float acc[8] = {0.f, 0.f, 0.f, 0.f, 0.f, 0.f, 0.f, 0.f};
  int lo = indptr[node], hi = indptr[node + 1];
  for (int j = lo; j < hi; ++j) {
    float a = alpha[j];
    uint4 u = *(const uint4*)(xpad + (size_t)csr_src[j] * 64 + l8 * 8);
    float v[8]; unp8(u, v);
#pragma unroll
    for (int t = 0; t < 8; ++t) acc[t] += a * v[t];
  }
  st8(xagg + (size_t)node * 64 + l8 * 8, acc);
}

// edge score: 4 edges/wave, 16-lane groups, uint4 loads (bf16, Fc multiple of 128)
template <bool ACCUM>
__global__ void edge_vec4_kernel(const bf16* __restrict__ xl, int ldxl,
                                 const bf16* __restrict__ xr, int ldxr,
                                 const int* __restrict__ csr_src, const int* __restrict__ csr_dst,
                                 const float* __restrict__ att, float* __restrict__ ev,
                                 int Etot, int Fc) {
  int gid = blockIdx.x * blockDim.x + threadIdx.x;
  int lane = threadIdx.x & 63;
  int grp = lane >> 4, l16 = lane & 15;
  int edge = (gid >> 6) * 4 + grp;
  if (edge >= Etot) return;
  int s = csr_src[edge], d = csr_dst[edge];
  const bf16* pl = xl + (size_t)s * ldxl;
  const bf16* pr = xr + (size_t)d * ldxr;
  float acc = 0.f;
  for (int f0 = l16 * 8; f0 < Fc; f0 += 128) {
    uint4 ul = *(const uint4*)(pl + f0);
    uint4 ur = *(const uint4*)(pr + f0);
    float l[8], r[8];
    unp8(ul, l); unp8(ur, r);
    float4 a0 = *(const float4*)(att + f0);
    float4 a1 = *(const float4*)(att + f0 + 4);
    float at[8] = {a0.x, a0.y, a0.z, a0.w, a1.x, a1.y, a1.z, a1.w};
#pragma unroll
    for (int j = 0; j < 8; ++j) {
      float h = l[j] + r[j];
      h = fmaxf(h, NEG_SLOPE * h);
      acc += h * at[j];
    }
  }
#pragma unroll
  for (int m = 1; m < 16; m <<= 1) acc += __shfl_xor(acc, m);
  if (l16 == 0) {
    if (ACCUM) ev[edge] += acc;
    else ev[edge] = acc;
  }
}

template <bool ACCUM>
static void launch_edge4(const bf16* xl, int ldxl, const bf16* xr, int ldxr,
                         const int* cs, const int* cd, const float* att, float* ev,
                         int Etot, int Fc, hipStream_t st) {
  int blocks = (Etot + 15) / 16;
  edge_vec4_kernel<ACCUM><<<blocks, 256, 0, st>>>(xl, ldxl, xr, ldxr, cs, cd, att, ev, Etot, Fc);
}

// aggregation: 4 nodes/wave, 16-lane groups, uint4 loads (bf16 src; Fc = NC8*128)
template <int NC8, typename TD>
__global__ void agg4_kernel(const bf16* __restrict__ xl, int ldx,
                            const float* __restrict__ alpha,
                            const int* __restrict__ csr_src, const int* __restrict__ indptr,
                            const float* __restrict__ bias,
                            TD* __restrict__ out, int ldout, int N, int relu) {
  int gid = blockIdx.x * blockDim.x + threadIdx.x;
  int lane = threadIdx.x & 63;
  int grp = lane >> 4, l16 = lane & 15;
  int node = (gid >> 6) * 4 + grp;
  if (node >= N) return;
  float acc[NC8][8];
#pragma unroll
  for (int c = 0; c < NC8; ++c) {
    float4 b0 = *(const float4*)(bias + c * 128 + l16 * 8);
    float4 b1 = *(const float4*)(bias + c * 128 + l16 * 8 + 4);
    acc[c][0] = b0.x; acc[c][1] = b0.y; acc[c][2] = b0.z; acc[c][3] = b0.w;
    acc[c][4] = b1.x; acc[c][5] = b1.y; acc[c][6] = b1.z; acc[c][7] = b1.w;
  }
  int lo = indptr[node], hi = indptr[node + 1];
  for (int j = lo; j < hi; ++j) {
    float a = alpha[j];
    const bf16* row = xl + (size_t)csr_src[j] * ldx;
#pragma unroll
    for (int c = 0; c < NC8; ++c) {
      uint4 u = *(const uint4*)(row + c * 128 + l16 * 8);
      float v[8]; unp8(u, v);
#pragma unroll
      for (int t = 0; t < 8; ++t) acc[c][t] += a * v[t];
    }
  }
#pragma unroll
  for (int c = 0; c < NC8; ++c) {
    if (relu)
#pragma unroll
      for (int t = 0; t < 8; ++t) acc[c][t] = fmaxf(acc[c][t], 0.f);
    st8(&out[(size_t)node * ldout + c * 128 + l16 * 8], acc[c]);
  }
}

template <int NC8, typename TD>
static void launch_agg4(const bf16* xl, int ldx, const float* alpha, const int* cs,
                        const int* ip, const float* bias, TD* out, int ldout, int N, int relu,
                        hipStream_t st) {
  int blocks = (N + 15) / 16;
  agg4_kernel<NC8, TD><<<blocks, 256, 0, st>>>(xl, ldx, alpha, cs, ip, bias, out, ldout, N, relu);
}

// ---------------- MFMA GEMM (fp32 weights, scalar-staged; fallback only) ----------------

template <bool DUAL, bool ACCUM, typename TCL, typename TCR>
__global__ __launch_bounds__(256)
void mfma_gemm_kernel(const bf16* __restrict__ A, int lda, int M, int K, int Kw,
                      const float* __restrict__ Wl, const float* __restrict__ Wr,
                      int ldw,
                      TCL* __restrict__ Cl, int ldcl, TCR* __restrict__ Cr, int ldcr) {
  __shared__ short As[128 * 40];
  __shared__ short Bls[64 * 40];
  __shared__ short Brs[64 * 40];
  int tid = threadIdx.x;
  int lane = tid & 63;
  int wave = tid >> 6;
  int wm = wave >> 1, wn = wave & 1;
  int nwg = gridDim.x * gridDim.y;
  int orig = blockIdx.y * gridDim.x + blockIdx.x;
  int q = nwg >> 3, r = nwg & 7;
  int xcd = orig & 7;
  int base = (xcd < r) ? xcd * (q + 1) : r * (q + 1) + (xcd - r) * q;
  int wg = base + (orig >> 3);
  int bx = wg % gridDim.x;
  int by = wg / gridDim.x;
  int bm = by * 128, bn = bx * 64;
  f32x4 accl[4][2] = {};
  f32x4 accr[4][2] = {};
  int kg = lane >> 4;
  int rr = lane & 15;

  for (int k0 = 0; k0 < K; k0 += 32) {
#pragma unroll
    for (int i = 0; i < 2; ++i) {
      int c = tid + i * 256;
      int r2 = c >> 2, cg = c & 3;
      int gr = bm + r2;
      uint4 u = make_uint4(0u, 0u, 0u, 0u);
      if (gr < M) u = *(const uint4*)(A + (size_t)gr * lda + k0 + cg * 8);
      *(uint4*)(As + r2 * 40 + cg * 8) = u;
    }
    {
      int c = tid & 63, kb = tid >> 6;
      bf16 pl[8], pr[8];
#pragma unroll
      for (int j = 0; j < 8; ++j) {
        int kk = k0 + kb * 8 + j;
        float vl = 0.f, vr = 0.f;
        if (kk < Kw) {
          size_t w = (size_t)kk * ldw + bn + c;
          vl = Wl[w];
          if (DUAL) vr = Wr[w];
        }
        pl[j] = __float2bfloat16(vl);
        if (DUAL) pr[j] = __float2bfloat16(vr);
      }
      *(uint4*)(Bls + c * 40 + kb * 8) = *(uint4*)pl;
      if (DUAL) *(uint4*)(Brs + c * 40 + kb * 8) = *(uint4*)pr;
    }
    __syncthreads();
    sh8 af[4], blf[2], brf[2];
#pragma unroll
    for (int mi = 0; mi < 4; ++mi)
      af[mi] = *(const sh8*)(As + (wm * 64 + mi * 16 + rr) * 40 + kg * 8);
#pragma unroll
    for (int ni = 0; ni < 2; ++ni) {
      blf[ni] = *(const sh8*)(Bls + (wn * 32 + ni * 16 + rr) * 40 + kg * 8);
      if (DUAL) brf[ni] = *(const sh8*)(Brs + (wn * 32 + ni * 16 + rr) * 40 + kg * 8);
    }
#pragma unroll
    for (int mi = 0; mi < 4; ++mi)
#pragma unroll
      for (int ni = 0; ni < 2; ++ni) {
        accl[mi][ni] = __builtin_amdgcn_mfma_f32_16x16x32_bf16(af[mi], blf[ni], accl[mi][ni], 0, 0, 0);
        if (DUAL)
          accr[mi][ni] = __builtin_amdgcn_mfma_f32_16x16x32_bf16(af[mi], brf[ni], accr[mi][ni], 0, 0, 0);
      }
    __syncthreads();
  }
  int cr0 = (lane >> 4) * 4;
#pragma unroll
  for (int mi = 0; mi < 4; ++mi)
#pragma unroll
    for (int j = 0; j < 4; ++j) {
      int gr = bm + wm * 64 + mi * 16 + cr0 + j;
      if (gr >= M) continue;
#pragma unroll
      for (int ni = 0; ni < 2; ++ni) {
        int gc = bn + wn * 32 + ni * 16 + rr;
        float vl = accl[mi][ni][j];
        size_t ol = (size_t)gr * ldcl + gc;
        if (ACCUM) vl += ldf(&Cl[ol]);
        stf(&Cl[ol], vl);
        if (DUAL) {
          float vr = accr[mi][ni][j];
          size_t orr = (size_t)gr * ldcr + gc;
          if (ACCUM) vr += ldf(&Cr[orr]);
          stf(&Cr[orr], vr);
        }
      }
    }
}

template <bool DUAL, typename TCL, typename TCR>
static void launch_mfma(const bf16* A, int lda, int M, int K, int Kw,
                        const float* Wl, const float* Wr, int ldw, int Fc,
                        TCL* Cl, int ldcl, TCR* Cr, int ldcr, bool accum, hipStream_t st) {
  dim3 grid(Fc / 64, (M + 127) / 128);
  if (accum)
    mfma_gemm_kernel<DUAL, true, TCL, TCR><<<grid, 256, 0, st>>>(A, lda, M, K, Kw, Wl, Wr, ldw, Cl, ldcl, Cr, ldcr);
  else
    mfma_gemm_kernel<DUAL, false, TCL, TCR><<<grid, 256, 0, st>>>(A, lda, M, K, Kw, Wl, Wr, ldw, Cl, ldcl, Cr, ldcr);
}

// ---------------- MFMA GEMM (pre-transposed bf16 weights [F,K]) ----------------
// global_load_lds staging, unpadded 32-short LDS rows (bank-uniform reads).

template <bool DUAL, bool BIASRELU, typename TCL, typename TCR>
__global__ __launch_bounds__(256)
void mfma_wt_gemm_kernel(const bf16* __restrict__ A, int lda, int M, int K,
                         const bf16* __restrict__ WTl, const bf16* __restrict__ WTr,
                         const float* __restrict__ bias,
                         TCL* __restrict__ Cl, int ldcl, TCR* __restrict__ Cr, int ldcr) {
  __shared__ short As[128 * 32];
  __shared__ short Bls[64 * 32];
  __shared__ short Brs[64 * 32];
  int tid = threadIdx.x;
  int lane = tid & 63;
  int wave = tid >> 6;
  int wm = wave >> 1, wn = wave & 1;
  int nwg = gridDim.x * gridDim.y;
  int orig = blockIdx.y * gridDim.x + blockIdx.x;
  int q = nwg >> 3, r = nwg & 7;
  int xcd = orig & 7;
  int base = (xcd < r) ? xcd * (q + 1) : r * (q + 1) + (xcd - r) * q;
  int wg = base + (orig >> 3);
  int bx = wg % gridDim.x;
  int by = wg / gridDim.x;
  int bm = by * 128, bn = bx * 64;
  f32x4 accl[4][2] = {};
  f32x4 accr[4][2] = {};
  int kg = lane >> 4;
  int rr = lane & 15;

  // staging layout: LDS-linear chunk c (16B) = row-major (row = c>>2, cc = c&3)
  // A: 512 chunks -> 2 issues/wave; B: 256 chunks -> 1 issue/wave
  int ca0 = wave * 64 + lane;
  int ca1 = (4 + wave) * 64 + lane;
  int ra0 = ca0 >> 2, cca0 = ca0 & 3;
  int ra1 = ca1 >> 2, cca1 = ca1 & 3;
  int gra0 = bm + ra0; if (gra0 >= M) gra0 = M - 1;   // clamp: garbage rows are discarded
  int gra1 = bm + ra1; if (gra1 >= M) gra1 = M - 1;
  int cb = wave * 64 + lane;
  int rb = cb >> 2, ccb = cb & 3;

  const bf16* pa0 = A + (size_t)gra0 * lda + cca0 * 8;
  const bf16* pa1 = A + (size_t)gra1 * lda + cca1 * 8;
  const bf16* pbl = WTl + (size_t)(bn + rb) * K + ccb * 8;
  const bf16* pbr = WTr + (size_t)(bn + rb) * K + ccb * 8;

  for (int k0 = 0; k0 < K; k0 += 32) {
    gload16(pa0 + k0, As + ca0 * 8);
    gload16(pa1 + k0, As + ca1 * 8);
    gload16(pbl + k0, Bls + cb * 8);
    if (DUAL) gload16(pbr + k0, Brs + cb * 8);
    __syncthreads();   // drains vmcnt(0) before barrier
    sh8 af[4], blf[2], brf[2];
#pragma unroll
    for (int mi = 0; mi < 4; ++mi)
      af[mi] = *(const sh8*)(As + (wm * 64 + mi * 16 + rr) * 32 + kg * 8);
#pragma unroll
    for (int ni = 0; ni < 2; ++ni) {
      blf[ni] = *(const sh8*)(Bls + (wn * 32 + ni * 16 + rr) * 32 + kg * 8);
      if (DUAL) brf[ni] = *(const sh8*)(Brs + (wn * 32 + ni * 16 + rr) * 32 + kg * 8);
    }
#pragma unroll
    for (int mi = 0; mi < 4; ++mi)
#pragma unroll
      for (int ni = 0; ni < 2; ++ni) {
        accl[mi][ni] = __builtin_amdgcn_mfma_f32_16x16x32_bf16(af[mi], blf[ni], accl[mi][ni], 0, 0, 0);
        if (DUAL)
          accr[mi][ni] = __builtin_amdgcn_mfma_f32_16x16x32_bf16(af[mi], brf[ni], accr[mi][ni], 0, 0, 0);
      }
    __syncthreads();
  }
  int cr0 = (lane >> 4) * 4;
#pragma unroll
  for (int mi = 0; mi < 4; ++mi)
#pragma unroll
    for (int j = 0; j < 4; ++j) {
      int gr = bm + wm * 64 + mi * 16 + cr0 + j;
      if (gr >= M) continue;
#pragma unroll
      for (int ni = 0; ni < 2; ++ni) {
        int gc = bn + wn * 32 + ni * 16 + rr;
        float vl = accl[mi][ni][j];
        if (BIASRELU) vl = fmaxf(vl + bias[gc], 0.f);
        stf(&Cl[(size_t)gr * ldcl + gc], vl);
        if (DUAL) stf(&Cr[(size_t)gr * ldcr + gc], accr[mi][ni][j]);
      }
    }
}

template <bool DUAL, bool BIASRELU, typename TCL, typename TCR>
static void launch_mfma_wt(const bf16* A, int lda, int M, int K,
                           const bf16* WTl, const bf16* WTr, const float* bias, int Fc,
                           TCL* Cl, int ldcl, TCR* Cr, int ldcr, hipStream_t st) {
  dim3 grid(Fc / 64, (M + 127) / 128);
  mfma_wt_gemm_kernel<DUAL, BIASRELU, TCL, TCR><<<grid, 256, 0, st>>>(A, lda, M, K, WTl, WTr,
                                                                      bias, Cl, ldcl, Cr, ldcr);
}

// ---------------- vector GEMM (fp32; slim L1 fallback + L5) ----------------

template <typename TA, typename TCL, typename TCR, bool DUAL, bool ACCUM>
__global__ __launch_bounds__(256)
void vgemm_kernel(const TA* __restrict__ A, int lda, int M, int K,
                  const float* __restrict__ Wl, const float* __restrict__ Wr,
                  int ldw, int Fc,
                  TCL* __restrict__ Cl, int ldcl, TCR* __restrict__ Cr, int ldcr) {
  __shared__ float As[BK][BM + 4];
  __shared__ float Bls[BK][BN];
  __shared__ float Brs[BK][BN];
  int tid = threadIdx.x;
  int tx = tid & 15, ty = tid >> 4;
  int bn = blockIdx.x * BN, bm = blockIdx.y * BM;
  float accl[4][4] = {};
  float accr[4][4] = {};
  for (int k0 = 0; k0 < K; k0 += BK) {
#pragma unroll
    for (int i = 0; i < 4; ++i) {
      int idx = tid + i * 256;
      int r = idx >> 4, c = idx & 15;
      int gr = bm + r, gc = k0 + c;
      As[c][r] = (gr < M && gc < K) ? ldf(&A[(size_t)gr * lda + gc]) : 0.f;
    }
#pragma unroll
    for (int i = 0; i < 4; ++i) {
      int idx = tid + i * 256;
      int c = idx >> 6, n = idx & 63;
      int gc = k0 + c, gn = bn + n;
      bool ok = (gc < K && gn < Fc);
      size_t w = (size_t)gc * ldw + gn;
      Bls[c][n] = ok ? Wl[w] : 0.f;
      if (DUAL) Brs[c][n] = ok ? Wr[w] : 0.f;
    }
    __syncthreads();
#pragma unroll
    for (int kk = 0; kk < BK; ++kk) {
      float4 a = *(const float4*)&As[kk][ty * 4];
      float4 bl = *(const float4*)&Bls[kk][tx * 4];
      float av[4] = {a.x, a.y, a.z, a.w};
      float blv[4] = {bl.x, bl.y, bl.z, bl.w};
      float brv[4] = {0.f, 0.f, 0.f, 0.f};
      if (DUAL) {
        float4 br = *(const float4*)&Brs[kk][tx * 4];
        brv[0] = br.x; brv[1] = br.y; brv[2] = br.z; brv[3] = br.w;
      }
#pragma unroll
      for (int i = 0; i < 4; ++i)
#pragma unroll
        for (int j = 0; j < 4; ++j) {
          accl[i][j] += av[i] * blv[j];
          if (DUAL) accr[i][j] += av[i] * brv[j];
        }
    }
    __syncthreads();
  }
#pragma unroll
  for (int i = 0; i < 4; ++i) {
    int gr = bm + ty * 4 + i;
    if (gr >= M) continue;
#pragma unroll
    for (int j = 0; j < 4; ++j) {
      int gn = bn + tx * 4 + j;
      if (gn >= Fc) continue;
      float vl = accl[i][j];
      size_t ol = (size_t)gr * ldcl + gn;
      if (ACCUM) vl += ldf(&Cl[ol]);
      stf(&Cl[ol], vl);
      if (DUAL) {
        float vr = accr[i][j];
        size_t orr = (size_t)gr * ldcr + gn;
        if (ACCUM) vr += ldf(&Cr[orr]);
        stf(&Cr[orr], vr);
      }
    }
  }
}

template <typename TA, typename TCL, typename TCR>
static void launch_vgemm(const TA* A, int lda, int M, int K,
                         const float* Wl, const float* Wr, int ldw, int Fc,
                         TCL* Cl, int ldcl, TCR* Cr, int ldcr, bool accum, hipStream_t st) {
  dim3 grid((Fc + BN - 1) / BN, (M + BM - 1) / BM);
  if (Wr) {
    if (accum) vgemm_kernel<TA, TCL, TCR, true, true><<<grid, 256, 0, st>>>(A, lda, M, K, Wl, Wr, ldw, Fc, Cl, ldcl, Cr, ldcr);
    else       vgemm_kernel<TA, TCL, TCR, true, false><<<grid, 256, 0, st>>>(A, lda, M, K, Wl, Wr, ldw, Fc, Cl, ldcl, Cr, ldcr);
  } else {
    if (accum) vgemm_kernel<TA, TCL, TCR, false, true><<<grid, 256, 0, st>>>(A, lda, M, K, Wl, Wl, ldw, Fc, Cl, ldcl, Cr, ldcr);
    else       vgemm_kernel<TA, TCL, TCR, false, false><<<grid, 256, 0, st>>>(A, lda, M, K, Wl, Wl, ldw, Fc, Cl, ldcl, Cr, ldcr);
  }
}

// ---------------- edge scores (scalar fallback variants) ----------------

template <typename TSL, typename TSR, bool ACCUM>
__global__ void edge_e_kernel(const TSL* __restrict__ xl, int ldxl,
                              const TSR* __restrict__ xr, int ldxr,
                              const int* __restrict__ csr_src, const int* __restrict__ csr_dst,
                              const float* __restrict__ att, float* __restrict__ ev,
                              int Etot, int Fc) {
  int gid = blockIdx.x * blockDim.x + threadIdx.x;
  int edge = gid >> 6;
  int lane = threadIdx.x & 63;
  if (edge >= Etot) return;
  int s = csr_src[edge], d = csr_dst[edge];
  const TSL* pl = xl + (size_t)s * ldxl;
  const TSR* pr = xr + (size_t)d * ldxr;
  float acc = 0.f;
  for (int f = lane; f < Fc; f += 64) {
    float h = ldf(&pl[f]) + ldf(&pr[f]);
    h = h > 0.f ? h : NEG_SLOPE * h;
    acc += h * att[f];
  }
#pragma unroll
  for (int off = 32; off > 0; off >>= 1) acc += __shfl_down(acc, off);
  if (lane == 0) {
    if (ACCUM) ev[edge] += acc;
    else ev[edge] = acc;
  }
}

template <typename TSL, typename TSR>
static void launch_edge(const TSL* xl, int ldxl, const TSR* xr, int ldxr,
                        const int* cs, const int* cd,
                        const float* att, float* ev, int Etot, int Fc, bool accum,
                        hipStream_t st) {
  int blocks = (int)(((long long)Etot * 64 + 255) / 256);
  if (accum) edge_e_kernel<TSL, TSR, true><<<blocks, 256, 0, st>>>(xl, ldxl, xr, ldxr, cs, cd, att, ev, Etot, Fc);
  else       edge_e_kernel<TSL, TSR, false><<<blocks, 256, 0, st>>>(xl, ldxl, xr, ldxr, cs, cd, att, ev, Etot, Fc);
}

template <typename TSL, typename TSR, bool ACCUM>
__global__ void edge_vec_kernel(const TSL* __restrict__ xl, int ldxl,
                                const TSR* __restrict__ xr, int ldxr,
                                const int* __restrict__ csr_src, const int* __restrict__ csr_dst,
                                const float* __restrict__ att, float* __restrict__ ev,
                                int Etot, int Fc) {
  int gid = blockIdx.x * blockDim.x + threadIdx.x;
  int edge = gid >> 6;
  int lane = threadIdx.x & 63;
  if (edge >= Etot) return;
  int s = csr_src[edge], d = csr_dst[edge];
  const TSL* pl = xl + (size_t)s * ldxl;
  const TSR* pr = xr + (size_t)d * ldxr;
  float acc = 0.f;
  for (int f = 2 * lane; f < Fc; f += 128) {
    float2 l = ld2f(pl + f);
    float2 r = ld2f(pr + f);
    float2 at = *(const float2*)(att + f);
    float h0 = l.x + r.x; h0 = h0 > 0.f ? h0 : NEG_SLOPE * h0;
    float h1 = l.y + r.y; h1 = h1 > 0.f ? h1 : NEG_SLOPE * h1;
    acc += h0 * at.x + h1 * at.y;
  }
#pragma unroll
  for (int off = 32; off > 0; off >>= 1) acc += __shfl_down(acc, off);
  if (lane == 0) {
    if (ACCUM) ev[edge] += acc;
    else ev[edge] = acc;
  }
}

template <typename TSL, typename TSR>
static void launch_edge_vec(const TSL* xl, int ldxl, const TSR* xr, int ldxr,
                            const int* cs, const int* cd,
                            const float* att, float* ev, int Etot, int Fc, bool accum,
                            hipStream_t st) {
  int blocks = (int)(((long long)Etot * 64 + 255) / 256);
  if (accum) edge_vec_kernel<TSL, TSR, true><<<blocks, 256, 0, st>>>(xl, ldxl, xr, ldxr, cs, cd, att, ev, Etot, Fc);
  else       edge_vec_kernel<TSL, TSR, false><<<blocks, 256, 0, st>>>(xl, ldxl, xr, ldxr, cs, cd, att, ev, Etot, Fc);
}

// ---------------- segment softmax ----------------

__global__ void softmax_kernel(float* __restrict__ ev, const int* __restrict__ indptr, int N) {
  int i = blockIdx.x * blockDim.x + threadIdx.x;
  if (i >= N) return;
  int lo = indptr[i], hi = indptr[i + 1];
  float m = -1e30f;
  for (int j = lo; j < hi; ++j) m = fmaxf(m, ev[j]);
  float s = 0.f;
  for (int j = lo; j < hi; ++j) { float x = expf(ev[j] - m); ev[j] = x; s += x; }
  float inv = 1.f / s;
  for (int j = lo; j < hi; ++j) ev[j] *= inv;
}

// ---------------- aggregation (scalar fallback; Fc = NP*128) ----------------

template <int NP, typename TS, typename TD>
__global__ void agg_vec_kernel(const TS* __restrict__ xl, int ldx,
                               const float* __restrict__ alpha,
                               const int* __restrict__ csr_src, const int* __restrict__ indptr,
                               const float* __restrict__ bias,
                               TD* __restrict__ out, int ldout, int N, int relu) {
  int gid = blockIdx.x * blockDim.x + threadIdx.x;
  int node = gid >> 6;
  int lane = threadIdx.x & 63;
  if (node >= N) return;
  float ax[NP], ay[NP];
#pragma unroll
  for (int p = 0; p < NP; ++p) {
    float2 b = *(const float2*)(bias + 2 * lane + p * 128);
    ax[p] = b.x; ay[p] = b.y;
  }
  int lo = indptr[node], hi = indptr[node + 1];
  for (int j = lo; j < hi; ++j) {
    float a = alpha[j];
    const TS* row = xl + (size_t)csr_src[j] * ldx;
#pragma unroll
    for (int p = 0; p < NP; ++p) {
      float2 v = ld2f(row + 2 * lane + p * 128);
      ax[p] += a * v.x;
      ay[p] += a * v.y;
    }
  }
#pragma unroll
  for (int p = 0; p < NP; ++p) {
    float vx = ax[p], vy = ay[p];
    if (relu) { vx = fmaxf(vx, 0.f); vy = fmaxf(vy, 0.f); }
    st2f(&out[(size_t)node * ldout + 2 * lane + p * 128], vx, vy);
  }
}

template <typename TS, typename TD>
static void launch_agg_vec(const TS* xl, int ldx, const float* alpha, const int* cs, const int* ip,
                           const float* bias, TD* out, int ldout, int N, int Fc, int relu,
                           hipStream_t st) {
  int blocks = (int)(((long long)N * 64 + 255) / 256);
  switch (Fc >> 7) {
    case 4: agg_vec_kernel<4, TS, TD><<<blocks, 256, 0, st>>>(xl, ldx, alpha, cs, ip, bias, out, ldout, N, relu); break;
    case 2: agg_vec_kernel<2, TS, TD><<<blocks, 256, 0, st>>>(xl, ldx, alpha, cs, ip, bias, out, ldout, N, relu); break;
    case 1: agg_vec_kernel<1, TS, TD><<<blocks, 256, 0, st>>>(xl, ldx, alpha, cs, ip, bias, out, ldout, N, relu); break;
  }
}

__global__ void aggregate3_kernel(const float* __restrict__ xl, const float* __restrict__ alpha,
                                  const int* __restrict__ csr_src, const int* __restrict__ indptr,
                                  const float* __restrict__ bias, float* __restrict__ out, int N) {
  int i = blockIdx.x * blockDim.x + threadIdx.x;
  if (i >= N) return;
  float a0 = bias[0], a1 = bias[1], a2 = bias[2];
  int lo = indptr[i], hi = indptr[i + 1];
  for (int j = lo; j < hi; ++j) {
    float a = alpha[j];
    const float* row = xl + (size_t)csr_src[j] * 3;
    a0 += a * row[0];
    a1 += a * row[1];
    a2 += a * row[2];
  }
  out[(size_t)i * 3 + 0] = a0;
  out[(size_t)i * 3 + 1] = a1;
  out[(size_t)i * 3 + 2] = a2;
}

// ---------------- launch ----------------

extern "C" void kernel_launch(void* const* d_in, const int* in_sizes, int n_in,
                              void* d_out, int out_size, void* d_ws, size_t ws_size,
                              hipStream_t stream) {
  const float* x = (const float*)d_in[0];
  const int* ei = (const int*)d_in[1];
  const int N = in_sizes[0] / 39;
  const int E = in_sizes[1] / 2;
  const int Etot = E + N;
  (void)n_in; (void)out_size;

  const float* Wl[5]; const float* Wr[5]; const float* att[5]; const float* bb[5];
  for (int l = 0; l < 5; ++l) {
    Wl[l]  = (const float*)d_in[2 + 4 * l];
    Wr[l]  = (const float*)d_in[3 + 4 * l];
    att[l] = (const float*)d_in[4 + 4 * l];
    bb[l]  = (const float*)d_in[5 + 4 * l];
  }

  char* ws = (char*)d_ws;
  size_t off = 0;
  auto alloc = [&](size_t b) -> char* {
    char* p = ws + off;
    off += (b + 255) & ~(size_t)255;
    return p;
  };
  int* counts  = (int*)alloc((size_t)N * 4);
  int* fillc   = (int*)alloc((size_t)N * 4);
  int* flag    = (int*)alloc(256);
  int* indptr  = (int*)alloc(((size_t)N + 1) * 4);
  int* csr_s   = (int*)alloc((size_t)Etot * 4);
  int* csr_d   = (int*)alloc((size_t)Etot * 4);
  float* ev    = (float*)alloc((size_t)Etot * 4);
  size_t small_end = off;

  const size_t fat4_need = small_end + (size_t)N * (2048 + 512) + 8192;
  const size_t slim_need = small_end + (size_t)Etot * 4 + (size_t)N * 2048 + 8192;
  if (ws_size < slim_need) return;

  const int tb = 256;
  init_counts_kernel<<<(N + tb - 1) / tb, tb, 0, stream>>>(counts, fillc, N, flag);
  detect_kernel<<<(E + tb - 1) / tb, tb, 0, stream>>>(ei, E, flag);
  count_kernel<<<(E + tb - 1) / tb, tb, 0, stream>>>(ei, E, flag, counts);
  scan_kernel<<<1, 256, 0, stream>>>(counts, indptr, N);
  fill_kernel<<<(Etot + tb - 1) / tb, tb, 0, stream>>>(ei, E, N, flag, indptr,
                                                       fillc, csr_s, csr_d);

  if (ws_size >= fat4_need) {
    // ======= FAT12 (reverted best): fused_score5 + gload mfma_wt 128x64 =======
    char* OU = alloc((size_t)N * 2048);
    char* W1 = alloc((size_t)N * 512);
    bf16* out1 = (bf16*)OU;
    bf16* XLsc = (bf16*)OU;
    bf16* xpad = (bf16*)W1;
    bf16* xagg = (bf16*)(W1 + (size_t)N * 256);
    bf16* S0 = (bf16*)W1;
    bf16* S1 = (bf16*)(W1 + (size_t)N * 256);
    bf16* Dfull = (bf16*)d_out;
    bf16* D0 = (bf16*)d_out;
    bf16* D1 = (bf16*)d_out + (size_t)N * 128;

    const size_t wt_bytes = ((size_t)512 * 1024 + 256 * 512 + 128 * 256) * 2 * 2 + 2048;
    bool use_wt = (ws_size >= off + wt_bytes);
    bf16 *WT2l = nullptr, *WT2r = nullptr, *WT3l = nullptr, *WT3r = nullptr,
         *WT4l = nullptr, *WT4r = nullptr;
    if (use_wt) {
      WT2l = (bf16*)alloc((size_t)512 * 1024 * 2);
      WT2r = (bf16*)alloc((size_t)512 * 1024 * 2);
      WT3l = (bf16*)alloc((size_t)256 * 512 * 2);
      WT3r = (bf16*)alloc((size_t)256 * 512 * 2);
      WT4l = (bf16*)alloc((size_t)128 * 256 * 2);
      WT4r = (bf16*)alloc((size_t)128 * 256 * 2);
      transpose_w_kernel<<<(512 * 1024 + tb - 1) / tb, tb, 0, stream>>>(Wl[1], WT2l, 1024, 512);
      transpose_w_kernel<<<(512 * 1024 + tb - 1) / tb, tb, 0, stream>>>(Wr[1], WT2r, 1024, 512);
      transpose_w_kernel<<<(256 * 512 + tb - 1) / tb, tb, 0, stream>>>(Wl[2], WT3l, 512, 256);
      transpose_w_kernel<<<(256 * 512 + tb - 1) / tb, tb, 0, stream>>>(Wr[2], WT3r, 512, 256);
      transpose_w_kernel<<<(128 * 256 + tb - 1) / tb, tb, 0, stream>>>(Wl[3], WT4l, 256, 128);
      transpose_w_kernel<<<(128 * 256 + tb - 1) / tb, tb, 0, stream>>>(Wr[3], WT4r, 256, 128);
    }
    bool use_f1 = use_wt;
    bf16* WT0l = (bf16*)((char*)d_out + (size_t)N * 512);   // [1024][64]  (128 KB)
    bf16* WTs2 = WT0l + (size_t)1024 * 64;                  // [1024][128] (256 KB)
    if (use_f1) {
      transpose_w_pad_kernel<<<(1024 * 64 + tb - 1) / tb, tb, 0, stream>>>(Wl[0], WT0l, 39, 64, 1024);
      wstack2_kernel<<<(1024 * 128 + tb - 1) / tb, tb, 0, stream>>>(Wl[0], Wr[0], WTs2);
    }

    convert_pad_kernel<<<(N * 64 + tb - 1) / tb, tb, 0, stream>>>(x, xpad, N);

    if (use_f1) {
      fused_score5_kernel<<<(Etot + 255) / 256, 256, 0, stream>>>(xpad, WTs2, att[0],
                                                                  csr_s, csr_d, ev, Etot);
      softmax_kernel<<<(N + tb - 1) / tb, tb, 0, stream>>>(ev, indptr, N);
      agg64v_kernel<<<(N + 31) / 32, 256, 0, stream>>>(xpad, ev, csr_s, indptr, xagg, N);
      launch_mfma_wt<false, true, bf16, bf16>(xagg, 64, N, 64, WT0l, WT0l, bb[0], 1024,
                                              out1, 1024, out1, 1024, stream);
    } else {
      for (int kc = 0; kc < 4; ++kc) {
        launch_mfma<true, bf16, bf16>(xpad, 64, N, 64, 39, Wl[0] + kc * 256, Wr[0] + kc * 256,
                                      1024, 256, XLsc, 256, Dfull, 256, false, stream);
        launch_edge_vec<bf16, bf16>(XLsc, 256, Dfull, 256, csr_s, csr_d, att[0] + kc * 256,
                                    ev, Etot, 256, kc > 0, stream);
      }
      softmax_kernel<<<(N + tb - 1) / tb, tb, 0, stream>>>(ev, indptr, N);
      for (int kc = 0; kc < 4; ++kc) {
        launch_mfma<false, bf16, bf16>(xpad, 64, N, 64, 39, Wl[0] + kc * 256, Wl[0] + kc * 256,
                                       1024, 256, Dfull, 256, Dfull, 256, false, stream);
        launch_agg_vec<bf16, bf16>(Dfull, 256, ev, csr_s, indptr, bb[0] + kc * 256,
                                   out1 + kc * 256, 1024, N, 256, 1, stream);
      }
    }
    // xpad/xagg dead -> S0/S1 usable

    // L2 scores: XL fc0->S0 (evicted by fc3), fc1->S1, fc2->D0, fc3->S0; XR home D1
    bf16* xlslot[4] = { S0, S1, D0, S0 };
    for (int fc = 0; fc < 4; ++fc) {
      if (use_wt)
        launch_mfma_wt<true, false, bf16, bf16>(out1, 1024, N, 1024,
                                                WT2l + (size_t)fc * 128 * 1024,
                                                WT2r + (size_t)fc * 128 * 1024, nullptr, 128,
                                                xlslot[fc], 128, D1, 128, stream);
      else
        launch_mfma<true, bf16, bf16>(out1, 1024, N, 1024, 1024, Wl[1] + fc * 128, Wr[1] + fc * 128,
                                      512, 128, xlslot[fc], 128, D1, 128, false, stream);
      if (fc > 0)
        launch_edge4<true>(xlslot[fc], 128, D1, 128, csr_s, csr_d, att[1] + fc * 128, ev, Etot, 128, stream);
      else
        launch_edge4<false>(xlslot[fc], 128, D1, 128, csr_s, csr_d, att[1], ev, Etot, 128, stream);
    }
    softmax_kernel<<<(N + tb - 1) / tb, tb, 0, stream>>>(ev, indptr, N);
    if (use_wt)
      launch_mfma_wt<false, false, bf16, bf16>(out1, 1024, N, 1024, WT2l, WT2l, nullptr, 128,
                                               D1, 128, D1, 128, stream);
    else
      launch_mfma<false, bf16, bf16>(out1, 1024, N, 1024, 1024, Wl[1], Wl[1],
                                     512, 128, D1, 128, D1, 128, false, stream);
    bf16* out2 = (bf16*)OU;
    launch_agg4<1, bf16>(D1, 128, ev, csr_s, indptr, bb[1] + 0 * 128, out2 + 0 * 128, 512, N, 1, stream);
    launch_agg4<1, bf16>(S1, 128, ev, csr_s, indptr, bb[1] + 1 * 128, out2 + 1 * 128, 512, N, 1, stream);
    launch_agg4<1, bf16>(D0, 128, ev, csr_s, indptr, bb[1] + 2 * 128, out2 + 2 * 128, 512, N, 1, stream);
    launch_agg4<1, bf16>(S0, 128, ev, csr_s, indptr, bb[1] + 3 * 128, out2 + 3 * 128, 512, N, 1, stream);

    // L3
    bf16* XL3 = (bf16*)(OU + (size_t)N * 1024);
    bf16* XR3 = (bf16*)(OU + (size_t)N * 1536);
    if (use_wt)
      launch_mfma_wt<true, false, bf16, bf16>(out2, 512, N, 512, WT3l, WT3r, nullptr, 256,
                                              XL3, 256, XR3, 256, stream);
    else
      launch_mfma<true, bf16, bf16>(out2, 512, N, 512, 512, Wl[2], Wr[2], 256, 256,
                                    XL3, 256, XR3, 256, false, stream);
    launch_edge4<false>(XL3, 256, XR3, 256, csr_s, csr_d, att[2], ev, Etot, 256, stream);
    softmax_kernel<<<(N + tb - 1) / tb, tb, 0, stream>>>(ev, indptr, N);
    bf16* out3 = XR3;
    launch_agg4<2, bf16>(XL3, 256, ev, csr_s, indptr, bb[2], out3, 256, N, 1, stream);

    // L4 -> d_out fp32
    bf16* XL4 = (bf16*)OU;
    bf16* XR4 = (bf16*)(OU + (size_t)N * 256);
    if (use_wt)
      launch_mfma_wt<true, false, bf16, bf16>(out3, 256, N, 256, WT4l, WT4r, nullptr, 128,
                                              XL4, 128, XR4, 128, stream);
    else
      launch_mfma<true, bf16, bf16>(out3, 256, N, 256, 256, Wl[3], Wr[3], 128, 128,
                                    XL4, 128, XR4, 128, false, stream);
    launch_edge4<false>(XL4, 128, XR4, 128, csr_s, csr_d, att[3], ev, Etot, 128, stream);
    softmax_kernel<<<(N + tb - 1) / tb, tb, 0, stream>>>(ev, indptr, N);
    launch_agg4<1, float>(XL4, 128, ev, csr_s, indptr, bb[3], (float*)d_out, 128, N, 1, stream);

    // L5
    float* XL5 = (float*)W1;
    float* XR5 = (float*)(W1 + (((size_t)N * 12 + 255) & ~(size_t)255));
    launch_vgemm<float, float, float>((const float*)d_out, 128, N, 128, Wl[4], Wr[4], 3, 3,
                                      XL5, 3, XR5, 3, false, stream);
    launch_edge<float, float>(XL5, 3, XR5, 3, csr_s, csr_d, att[4], ev, Etot, 3, false, stream);
    softmax_kernel<<<(N + tb - 1) / tb, tb, 0, stream>>>(ev, indptr, N);
    aggregate3_kernel<<<(N + tb - 1) / tb, tb, 0, stream>>>(XL5, ev, csr_s, indptr, bb[4],
                                                            (float*)d_out + (size_t)N * 128, N);
    return;
  }

  // ============ SLIM-5 (verified fallback) ============
  float* alpha1 = (float*)alloc((size_t)Etot * 4);
  char* R0 = alloc((size_t)N * 256);
  char* R1 = alloc((size_t)N * 256);
  char* R2 = alloc((size_t)N * 512);
  char* R3 = alloc((size_t)N * 512);
  char* R4 = alloc((size_t)N * 512);
  (void)R4;
  size_t base_need = off + 4096;
  bool use_xpad = (ws_size >= base_need + (size_t)N * 128 + 256);
  bf16* xpad = use_xpad ? (bf16*)alloc((size_t)N * 128) : nullptr;

  bf16* xl1c = (bf16*)R0;
  bf16* t1   = (bf16*)R1;
  float* waccL = (float*)R2;
  float* waccR = (float*)R3;
  bf16* out2 = (bf16*)R3;
  bf16* dXL1 = (bf16*)d_out;
  bf16* dXL2 = (bf16*)d_out + (size_t)N * 128;

  if (use_xpad)
    convert_pad_kernel<<<(N * 64 + tb - 1) / tb, tb, 0, stream>>>(x, xpad, N);

  for (int kc = 0; kc < 8; ++kc) {
    if (use_xpad)
      launch_mfma<true, bf16, bf16>(xpad, 64, N, 64, 39, Wl[0] + kc * 128, Wr[0] + kc * 128,
                                    1024, 128, xl1c, 128, t1, 128, false, stream);
    else
      launch_vgemm<float, bf16, bf16>(x, 39, N, 39, Wl[0] + kc * 128, Wr[0] + kc * 128, 1024, 128,
                                      xl1c, 128, t1, 128, false, stream);
    launch_edge_vec<bf16, bf16>(xl1c, 128, t1, 128, csr_s, csr_d, att[0] + kc * 128,
                                ev, Etot, 128, kc > 0, stream);
  }
  softmax_kernel<<<(N + tb - 1) / tb, tb, 0, stream>>>(ev, indptr, N);
  copy_kernel<<<(Etot + tb - 1) / tb, tb, 0, stream>>>(ev, alpha1, Etot);

  auto mat_out1 = [&](int kc) {
    if (use_xpad)
      launch_mfma<false, bf16, bf16>(xpad, 64, N, 64, 39, Wl[0] + kc * 128, Wl[0] + kc * 128,
                                     1024, 128, xl1c, 128, xl1c, 128, false, stream);
    else
      launch_vgemm<float, bf16, bf16>(x, 39, N, 39, Wl[0] + kc * 128, nullptr, 1024, 128,
                                      xl1c, 128, xl1c, 128, false, stream);
    launch_agg_vec<bf16, bf16>(xl1c, 128, alpha1, csr_s, indptr, bb[0] + kc * 128,
                               t1, 128, N, 128, 1, stream);
  };

  for (int fc = 0; fc < 4; ++fc) {
    for (int kc = 0; kc < 8; ++kc) {
      mat_out1(kc);
      const float* wl = Wl[1] + (size_t)kc * 128 * 512 + fc * 128;
      const float* wr = Wr[1] + (size_t)kc * 128 * 512 + fc * 128;
      launch_mfma<true, float, float>(t1, 128, N, 128, 128, wl, wr, 512, 128,
                                      waccL, 128, waccR, 128, kc > 0, stream);
    }
    launch_edge_vec<float, float>(waccL, 128, waccR, 128, csr_s, csr_d,
                                  att[1] + fc * 128, ev, Etot, 128, fc > 0, stream);
    if (fc == 1)
      f2b_kernel<<<(N * 64 + tb - 1) / tb, tb, 0, stream>>>(waccL, dXL1, N * 64);
    if (fc == 2)
      f2b_kernel<<<(N * 64 + tb - 1) / tb, tb, 0, stream>>>(waccL, dXL2, N * 64);
  }
  softmax_kernel<<<(N + tb - 1) / tb, tb, 0, stream>>>(ev, indptr, N);

  launch_agg_vec<float, bf16>(waccL, 128, ev, csr_s, indptr, bb[1] + 3 * 128,
                              out2 + 3 * 128, 512, N, 128, 1, stream);
  launch_agg_vec<bf16, bf16>(dXL1, 128, ev, csr_s, indptr, bb[1] + 1 * 128,
                             out2 + 1 * 128, 512, N, 128, 1, stream);
  launch_agg_vec<bf16, bf16>(dXL2, 128, ev, csr_s, indptr, bb[1] + 2 * 128,
                             out2 + 2 * 128, 512, N, 128, 1, stream);
  for (int kc = 0; kc < 8; ++kc) {
    mat_out1(kc);
    const float* wl = Wl[1] + (size_t)kc * 128 * 512;
    launch_mfma<false, float, float>(t1, 128, N, 128, 128, wl, wl, 512, 128,
                                     waccL, 128, waccL, 128, kc > 0, stream);
  }
  launch_agg_vec<float, bf16>(waccL, 128, ev, csr_s, indptr, bb[1],
                              out2, 512, N, 128, 1, stream);

  bf16* XL3 = (bf16*)R2;
  bf16* XR3 = (bf16*)R0;
  launch_mfma<true, bf16, bf16>(out2, 512, N, 512, 512, Wl[2], Wr[2], 256, 256,
                                XL3, 256, XR3, 256, false, stream);
  launch_edge_vec<bf16, bf16>(XL3, 256, XR3, 256, csr_s, csr_d, att[2], ev, Etot, 256, false, stream);
  softmax_kernel<<<(N + tb - 1) / tb, tb, 0, stream>>>(ev, indptr, N);
  bf16* out3 = XR3;
  launch_agg_vec<bf16, bf16>(XL3, 256, ev, csr_s, indptr, bb[2], out3, 256, N, 256, 1, stream);

  bf16* XL4 = (bf16*)R2;
  bf16* XR4 = (bf16*)(R2 + (size_t)N * 256);
  launch_mfma<true, bf16, bf16>(out3, 256, N, 256, 256, Wl[3], Wr[3], 128, 128,
                                XL4, 128, XR4, 128, false, stream);
  launch_edge_vec<bf16, bf16>(XL4, 128, XR4, 128, csr_s, csr_d, att[3], ev, Etot, 128, false, stream);
  softmax_kernel<<<(N + tb - 1) / tb, tb, 0, stream>>>(ev, indptr, N);
  launch_agg_vec<bf16, float>(XL4, 128, ev, csr_s, indptr, bb[3], (float*)d_out, 128, N, 128, 1, stream);

  float* XL5 = (float*)R3;
  float* XR5 = (float*)(R3 + (((size_t)N * 12 + 255) & ~(size_t)255));
  launch_vgemm<float, float, float>((const float*)d_out, 128, N, 128, Wl[4], Wr[4], 3, 3,
                                    XL5, 3, XR5, 3, false, stream);
  launch_edge<float, float>(XL5, 3, XR5, 3, csr_s, csr_d, att[4], ev, Etot, 3, false, stream);
  softmax_kernel<<<(N + tb - 1) / tb, tb, 0, stream>>>(ev, indptr, N);
  aggregate3_kernel<<<(N + tb - 1) / tb, tb, 0, stream>>>(XL5, ev, csr_s, indptr, bb[4],
                                                          (float*)d_out + (size_t)N * 128, N);
}